// Round 9
// baseline (429.519 us; speedup 1.0000x reference)
//
#include <hip/hip_runtime.h>
#include <hip/hip_bf16.h>

// HeteroSAGE collapsed pipeline (float32 I/O, bf16 MFMA + bf16 intermediates):
//   out[i] = mean_cites(s_c[src]) + mean_writes(s_w[src]) + s_r[i] + C0
//   s_c = p1.(W2l_c@Wh), s_r = p1.((W2r_c+W2r_w)@Wh), s_w = a1.(W2l_w@Wh)
//   p1 = relu(mean_c(YpC[src]) + mean_w(YaW[src]) + YpD + b1c + b1w)
//   a1 = relu(mean_r(YpR[src]) + YaD + b1rev)
// R8: direct-claim scatter -> mid 143us. R9: SPAN 2048 -> mid 125us, occ 51%
// (pre-commit: if dur stalls while occ rises, pole = gcur atomic contention).
// R10: fused sort+agg (VERIFIED). R11-R13: LDS-atomic agg CONVICTED (post-
// timing divergence) -- do not revisit. R14: revert verified 397.5us. R15:
// prep grid-stride + gatherCW -> 377.6us (prep branch of prediction => sagg
// gathers were NOT the pole). R16 (this round): honor R9's pre-commitment.
// mid shows everything idle (VALU 5%, HBM 19%, occ 51%) -- the ~1.76M
// device-scope claim atomics land on gcur = 18.7KB = 293 cache lines (~6000
// contended far-atomic hits/line, serialized at the coherence point since
// per-XCD L2s are non-coherent). Fix: pad each counter to its own 64B line
// (gcur[i] -> gcur[i*16], 300KB ws). Predict mid 128 -> ~95-110us; if mid
// moves <5us the theory is refuted -> next suspect is ebuf 4B-store line
// dirty amplification (WRITE 115MB vs 39MB ideal).

#define SPAN  2048
#define EPT   8           // SPAN / 256 edges per thread
#define NBKT  1563        // ceil(200000/128) == ceil(100000/64)
#define CAP   1024        // padded region per (rel,bucket); Poisson(640), 15 sigma
#define SMASK 0x3FFFF     // 18-bit src index (200000 < 2^18)
#define GPAD  16          // gcur counter stride in ints (one 64B line each)

typedef __bf16 bf16x8 __attribute__((ext_vector_type(8)));
typedef __bf16 bf16x2 __attribute__((ext_vector_type(2)));
typedef float f32x4 __attribute__((ext_vector_type(4)));

// ---------------- prep: weights -> bf16, head vecs, cursor init ----------------
// Grid-strided across blocks; only block 0 computes the 32-wide uvec collapse.
__global__ void prep_kernel(const float* W1l_c, const float* W1l_rev,
                            const float* W1r_c, const float* W1r_w,
                            const float* W1l_w, const float* W1r_rev,
                            const float* W2l_c, const float* W2l_w,
                            const float* W2r_c, const float* W2r_w,
                            const float* b2l_c, const float* b2l_w,
                            const float* Wh, const float* bh,
                            __bf16* Bp_t, __bf16* Ba_t, float* uvec, int* gcur) {
    int tid = blockIdx.x * 256 + threadIdx.x;
    int nthr = gridDim.x * 256;
    for (int i = tid; i < 3 * NBKT; i += nthr) gcur[i * GPAD] = i << 10;  // padded bases
    for (int idx = tid; idx < 96 * 128; idx += nthr) {   // Bp_t[n][k] n<96,k<128
        int n = idx >> 7, k = idx & 127;
        float v;
        if (n < 32)      v = W1l_c[k * 32 + n];
        else if (n < 64) v = W1l_rev[k * 32 + (n - 32)];
        else             v = W1r_c[k * 32 + (n - 64)] + W1r_w[k * 32 + (n - 64)];
        Bp_t[n * 128 + k] = (__bf16)v;
    }
    for (int idx = tid; idx < 64 * 64; idx += nthr) {    // Ba_t[n][k] n<64,k<64
        int n = idx >> 6, k = idx & 63;
        float v = (n < 32) ? W1l_w[k * 32 + n] : W1r_rev[k * 32 + (n - 32)];
        Ba_t[n * 64 + k] = (__bf16)v;
    }
    if (blockIdx.x == 0 && threadIdx.x < 32) {
        int t = threadIdx.x;
        float uc = 0.f, uw = 0.f, ur = 0.f;
        for (int j = 0; j < 32; ++j) {
            float wh = Wh[j];
            uc += W2l_c[t * 32 + j] * wh;
            uw += W2l_w[t * 32 + j] * wh;
            ur += (W2r_c[t * 32 + j] + W2r_w[t * 32 + j]) * wh;
        }
        uvec[t] = uc; uvec[32 + t] = uw; uvec[64 + t] = ur;
        if (t == 0) {
            float c0 = bh[0];
            for (int j = 0; j < 32; ++j) c0 += (b2l_c[j] + b2l_w[j]) * Wh[j];
            uvec[96] = c0;
        }
    }
}

// ---------------- proj body (MFMA 16x16x32 bf16), 32-col group split -----------
template <int K, int NG>
__device__ __forceinline__ void proj_body(const float* __restrict__ X,
                                          const __bf16* __restrict__ Bt,
                                          __bf16* __restrict__ D0,
                                          __bf16* __restrict__ D1,
                                          __bf16* __restrict__ D2, int M, int bid) {
    constexpr int NT = NG * 2, KT = K / 32;
    int lane = threadIdx.x & 63;
    int wave = (bid * 256 + (int)threadIdx.x) >> 6;
    int m0 = wave * 16;
    if (m0 + 16 > M) return;  // M % 16 == 0 here
    int lr = lane & 15;
    int quad = lane >> 4;

    bf16x8 bfrag[NT][KT];
#pragma unroll
    for (int ct = 0; ct < NT; ++ct)
#pragma unroll
        for (int ks = 0; ks < KT; ++ks)
            bfrag[ct][ks] = *(const bf16x8*)(Bt + (ct * 16 + lr) * K + ks * 32 + quad * 8);

    bf16x8 afrag[KT];
    const float* xrow = X + (size_t)(m0 + lr) * K + quad * 8;
#pragma unroll
    for (int ks = 0; ks < KT; ++ks) {
        f32x4 lo = *(const f32x4*)(xrow + ks * 32);
        f32x4 hi = *(const f32x4*)(xrow + ks * 32 + 4);
        bf16x8 a;
#pragma unroll
        for (int j = 0; j < 4; ++j) { a[j] = (__bf16)lo[j]; a[4 + j] = (__bf16)hi[j]; }
        afrag[ks] = a;
    }

    int odd = lane & 1;
#pragma unroll
    for (int ct = 0; ct < NT; ++ct) {
        f32x4 acc = {0.f, 0.f, 0.f, 0.f};
#pragma unroll
        for (int ks = 0; ks < KT; ++ks)
            acc = __builtin_amdgcn_mfma_f32_16x16x32_bf16(afrag[ks], bfrag[ct][ks], acc, 0, 0, 0);
        __bf16* D = ((ct >> 1) == 0) ? D0 : (((ct >> 1) == 1) ? D1 : D2);
        int col = (ct & 1) * 16 + lr;
        int cw = col & ~1;                 // even col of the lane pair
        int rbase = m0 + quad * 4;
        float o0 = __shfl_xor(acc[0], 1, 64);
        float o1 = __shfl_xor(acc[1], 1, 64);
        float o2 = __shfl_xor(acc[2], 1, 64);
        float o3 = __shfl_xor(acc[3], 1, 64);
        float s0 = odd ? o2 : acc[0], t0 = odd ? acc[2] : o0;   // row rb+0
        float s1 = odd ? o3 : acc[1], t1 = odd ? acc[3] : o1;   // row rb+1
        int rb = rbase + odd * 2;
        bf16x2 v0; v0[0] = (__bf16)s0; v0[1] = (__bf16)t0;
        bf16x2 v1; v1[0] = (__bf16)s1; v1[1] = (__bf16)t1;
        *(bf16x2*)(D + (size_t)(rb + 0) * 32 + cw) = v0;
        *(bf16x2*)(D + (size_t)(rb + 1) * 32 + cw) = v1;
    }
}

// ---------------- scatter body: direct-claim, arrival-order bucket fill --------
__device__ void scatter_body(const int* __restrict__ eiC, const int* __restrict__ eiW,
                             const int* __restrict__ eiR, int* __restrict__ gcur,
                             unsigned* __restrict__ ebuf, int E, int npart, int bid,
                             int* cnt) {
    int rel = bid / npart, blk = bid % npart;
    const int* ei = rel == 0 ? eiC : (rel == 1 ? eiW : eiR);
    int shift = (rel == 2) ? 6 : 7;
    unsigned dmask = (1u << shift) - 1;
    int t = threadIdx.x;
    int e0 = blk * SPAN, e1 = min(E, e0 + SPAN);
    for (int i = t; i < NBKT; i += 256) cnt[i] = 0;
    __syncthreads();
    int d8[EPT], s8[EPT];
#pragma unroll
    for (int j = 0; j < EPT; ++j) {
        int e = e0 + t + j * 256;
        if (e < e1) {
            d8[j] = ei[E + e];
            s8[j] = ei[e];
            atomicAdd(&cnt[d8[j] >> shift], 1);
        } else {
            d8[j] = -1;
        }
    }
    __syncthreads();
    for (int i = t; i < NBKT; i += 256) {
        int c = cnt[i];
        cnt[i] = c ? atomicAdd(&gcur[(rel * NBKT + i) * GPAD], c) : 0;
    }
    __syncthreads();
#pragma unroll
    for (int j = 0; j < EPT; ++j) {
        if (d8[j] >= 0) {
            int b = d8[j] >> shift;
            int gpos = atomicAdd(&cnt[b], 1);
            if (gpos < (((rel * NBKT + b) + 1) << 10))   // capacity clamp (~never)
                ebuf[gpos] = ((unsigned)(d8[j] & dmask) << 18) | (unsigned)s8[j];
        }
    }
}

// ---------------- mid: scatter FIRST (long pole), then proj blocks -------------
__global__ __launch_bounds__(256) void mid_kernel(
    const float* __restrict__ Xp, const float* __restrict__ Xa,
    const __bf16* __restrict__ Bp_t, const __bf16* __restrict__ Ba_t,
    __bf16* __restrict__ YpC, __bf16* __restrict__ YpR, __bf16* __restrict__ YpD,
    __bf16* __restrict__ YaW, __bf16* __restrict__ YaD,
    const int* __restrict__ eiC, const int* __restrict__ eiW,
    const int* __restrict__ eiR, int* __restrict__ gcur,
    unsigned* __restrict__ ebuf, int NP, int NA, int E,
    int nPp, int nPa, int npart) {
    __shared__ int cnt[NBKT];     // 6.25 KB -> wave-limited occupancy, not LDS
    int bid = blockIdx.x;
    if (bid < 3 * npart) {
        scatter_body(eiC, eiW, eiR, gcur, ebuf, E, npart, bid, cnt);
        return;
    }
    bid -= 3 * npart;
    if (bid < nPp) { proj_body<128, 3>(Xp, Bp_t, YpC, YpR, YpD, NP, bid); return; }
    bid -= nPp;
    proj_body<64, 2>(Xa, Ba_t, YaW, YaD, nullptr, NA, bid);
}

// ---------------- LDS-list gather: 4 independent Y-row loads in flight ---------
// lst is LDS (sorted plain src); 16 lanes cover channels 2*l16, 2*l16+1.
__device__ __forceinline__ float2 gatherL(const __bf16* __restrict__ S,
                                          const unsigned* __restrict__ lst,
                                          int o, int n, int l16) {
    float x = 0.f, y = 0.f;
    for (int e = 0; e < n; e += 4) {
        int m = n - e;
        unsigned s0 = lst[o + e];
        unsigned s1 = (m > 1) ? lst[o + e + 1] : s0;
        unsigned s2 = (m > 2) ? lst[o + e + 2] : s0;
        unsigned s3 = (m > 3) ? lst[o + e + 3] : s0;
        bf16x2 v0 = *(const bf16x2*)(S + (size_t)s0 * 32 + 2 * l16);
        bf16x2 v1 = *(const bf16x2*)(S + (size_t)s1 * 32 + 2 * l16);
        bf16x2 v2 = *(const bf16x2*)(S + (size_t)s2 * 32 + 2 * l16);
        bf16x2 v3 = *(const bf16x2*)(S + (size_t)s3 * 32 + 2 * l16);
        x += (float)v0[0]; y += (float)v0[1];
        if (m > 1) { x += (float)v1[0]; y += (float)v1[1]; }
        if (m > 2) { x += (float)v2[0]; y += (float)v2[1]; }
        if (m > 3) { x += (float)v3[0]; y += (float)v3[1]; }
    }
    return make_float2(x, y);
}

// ---------------- merged C+W gather: 8 independent Y-row loads in flight -------
// Two independent (list, Y) pairs for the same node; per-list accumulation
// order identical to gatherL -> bit-identical results. Empty/short lists fall
// back to index 0 (always a valid Y row); accumulation is predicate-guarded.
__device__ __forceinline__ void gatherCW(const __bf16* __restrict__ YA,
                                         const __bf16* __restrict__ YB,
                                         const unsigned* __restrict__ LA,
                                         const unsigned* __restrict__ LB,
                                         int oA, int nA, int oB, int nB, int l16,
                                         float2& rA, float2& rB) {
    float xA = 0.f, yA = 0.f, xB = 0.f, yB = 0.f;
    int nm = max(nA, nB);
    for (int e = 0; e < nm; e += 4) {
        unsigned a0 = (e + 0 < nA) ? LA[oA + e + 0] : 0u;
        unsigned a1 = (e + 1 < nA) ? LA[oA + e + 1] : 0u;
        unsigned a2 = (e + 2 < nA) ? LA[oA + e + 2] : 0u;
        unsigned a3 = (e + 3 < nA) ? LA[oA + e + 3] : 0u;
        unsigned b0 = (e + 0 < nB) ? LB[oB + e + 0] : 0u;
        unsigned b1 = (e + 1 < nB) ? LB[oB + e + 1] : 0u;
        unsigned b2 = (e + 2 < nB) ? LB[oB + e + 2] : 0u;
        unsigned b3 = (e + 3 < nB) ? LB[oB + e + 3] : 0u;
        bf16x2 vA0 = *(const bf16x2*)(YA + (size_t)a0 * 32 + 2 * l16);
        bf16x2 vA1 = *(const bf16x2*)(YA + (size_t)a1 * 32 + 2 * l16);
        bf16x2 vA2 = *(const bf16x2*)(YA + (size_t)a2 * 32 + 2 * l16);
        bf16x2 vA3 = *(const bf16x2*)(YA + (size_t)a3 * 32 + 2 * l16);
        bf16x2 vB0 = *(const bf16x2*)(YB + (size_t)b0 * 32 + 2 * l16);
        bf16x2 vB1 = *(const bf16x2*)(YB + (size_t)b1 * 32 + 2 * l16);
        bf16x2 vB2 = *(const bf16x2*)(YB + (size_t)b2 * 32 + 2 * l16);
        bf16x2 vB3 = *(const bf16x2*)(YB + (size_t)b3 * 32 + 2 * l16);
        if (e + 0 < nA) { xA += (float)vA0[0]; yA += (float)vA0[1]; }
        if (e + 1 < nA) { xA += (float)vA1[0]; yA += (float)vA1[1]; }
        if (e + 2 < nA) { xA += (float)vA2[0]; yA += (float)vA2[1]; }
        if (e + 3 < nA) { xA += (float)vA3[0]; yA += (float)vA3[1]; }
        if (e + 0 < nB) { xB += (float)vB0[0]; yB += (float)vB0[1]; }
        if (e + 1 < nB) { xB += (float)vB1[0]; yB += (float)vB1[1]; }
        if (e + 2 < nB) { xB += (float)vB2[0]; yB += (float)vB2[1]; }
        if (e + 3 < nB) { xB += (float)vB3[0]; yB += (float)vB3[1]; }
    }
    rA = make_float2(xA, yA);
    rB = make_float2(xB, yB);
}

// ---------------- sagg: fused per-bucket sort + aggregate + collapse -----------
// blocks [0,NBKT): paper bucket b (rel0 cites + rel1 writes), 128 nodes.
// blocks [NBKT,2*NBKT): author bucket b (rel2), 64 nodes, no write-back.
__global__ __launch_bounds__(256) void sagg_kernel(
    const __bf16* __restrict__ YpC, const __bf16* __restrict__ YaW,
    const __bf16* __restrict__ YpD, const __bf16* __restrict__ YpR,
    const __bf16* __restrict__ YaD, unsigned* __restrict__ ebuf,
    const int* __restrict__ gcur, int* __restrict__ nstart, int* __restrict__ ncnt,
    const float* __restrict__ b1l_c, const float* __restrict__ b1l_w,
    const float* __restrict__ b1l_r, const float* __restrict__ uvec,
    float* __restrict__ s_c, float* __restrict__ s_r, float* __restrict__ s_w,
    int NP, int NA) {
    __shared__ unsigned S0[CAP], S1[CAP];
    __shared__ int cnt0[128], exc0[128], cur0[128];
    __shared__ int cnt1[128], exc1[128], cur1[128];
    __shared__ int scan[256];
    const int NPS = NBKT * 128;
    int t = threadIdx.x;
    int sg = t >> 4, l16 = t & 15, c2 = 2 * l16;
    int bid = blockIdx.x;

    if (bid < NBKT) {
        // ---------------- papers ----------------
        int b = bid;
        int i0 = b, i1 = NBKT + b;
        int st0 = i0 << 10, st1 = i1 << 10;
        int n0 = min(gcur[i0 * GPAD] - st0, CAP), n1 = min(gcur[i1 * GPAD] - st1, CAP);
        if (t < 128) { cnt0[t] = 0; cnt1[t] = 0; }
        __syncthreads();
        for (int i = t; i < n0; i += 256) atomicAdd(&cnt0[ebuf[st0 + i] >> 18], 1);
        for (int i = t; i < n1; i += 256) atomicAdd(&cnt1[ebuf[st1 + i] >> 18], 1);
        __syncthreads();
        // dual 128-wide exclusive scan with 256 threads
        int own = (t < 128) ? cnt0[t] : cnt1[t - 128];
        scan[t] = own;
        __syncthreads();
        for (int d = 1; d < 128; d <<= 1) {
            int nv = scan[t] + (((t & 127) >= d) ? scan[t - d] : 0);
            __syncthreads();
            scan[t] = nv;
            __syncthreads();
        }
        int excl = scan[t] - own;
        if (t < 128) { exc0[t] = excl; cur0[t] = excl; }
        else         { exc1[t - 128] = excl; cur1[t - 128] = excl; }
        __syncthreads();
        // scatter into sorted LDS lists (plain src)
        for (int i = t; i < n0; i += 256) {
            unsigned w = ebuf[st0 + i];
            int pos = atomicAdd(&cur0[w >> 18], 1);
            S0[pos] = w & SMASK;
        }
        for (int i = t; i < n1; i += 256) {
            unsigned w = ebuf[st1 + i];
            int pos = atomicAdd(&cur1[w >> 18], 1);
            S1[pos] = w & SMASK;
        }
        __syncthreads();
        // fire-and-forget write-back for out_kernel (sorted lists + offsets)
        for (int i = t; i < n0; i += 256) ebuf[st0 + i] = S0[i];
        for (int i = t; i < n1; i += 256) ebuf[st1 + i] = S1[i];
        if (t < 128) {
            nstart[b * 128 + t] = st0 + exc0[t];
            ncnt[b * 128 + t] = cnt0[t];
            nstart[NPS + b * 128 + t] = st1 + exc1[t];
            ncnt[NPS + b * 128 + t] = cnt1[t];
        }
        // gather+combine: subgroup sg owns nodes sg*8 .. sg*8+7
        float u0 = uvec[c2], u1 = uvec[c2 + 1];
        float w0 = uvec[64 + c2], w1 = uvec[64 + c2 + 1];
        float bc0 = b1l_c[c2] + b1l_w[c2], bc1 = b1l_c[c2 + 1] + b1l_w[c2 + 1];
        for (int k = 0; k < 8; ++k) {
            int nd = sg * 8 + k;
            int g = b * 128 + nd;
            if (g >= NP) break;
            int nC = cnt0[nd], nW = cnt1[nd];
            float2 aC, aW;
            gatherCW(YpC, YaW, S0, S1, exc0[nd], nC, exc1[nd], nW, l16, aC, aW);
            float rC = 1.f / (float)max(nC, 1), rW = 1.f / (float)max(nW, 1);
            bf16x2 d = *(const bf16x2*)(YpD + (size_t)g * 32 + c2);
            float p0 = fmaxf(aC.x * rC + aW.x * rW + (float)d[0] + bc0, 0.f);
            float p1 = fmaxf(aC.y * rC + aW.y * rW + (float)d[1] + bc1, 0.f);
            float vc = p0 * u0 + p1 * u1;
            float vr = p0 * w0 + p1 * w1;
            for (int m = 1; m < 16; m <<= 1) {
                vc += __shfl_xor(vc, m, 64); vr += __shfl_xor(vr, m, 64);
            }
            if (l16 == 0) { s_c[g] = vc; s_r[g] = vr; }
        }
    } else {
        // ---------------- authors ----------------
        int b = bid - NBKT;
        int i2 = 2 * NBKT + b;
        int st2 = i2 << 10;
        int n2 = min(gcur[i2 * GPAD] - st2, CAP);
        if (t < 128) { cnt0[t] = 0; cnt1[t] = 0; }
        __syncthreads();
        for (int i = t; i < n2; i += 256) atomicAdd(&cnt0[ebuf[st2 + i] >> 18], 1);
        __syncthreads();
        int own = (t < 128) ? cnt0[t] : 0;
        scan[t] = own;
        __syncthreads();
        for (int d = 1; d < 128; d <<= 1) {
            int nv = scan[t] + (((t & 127) >= d) ? scan[t - d] : 0);
            __syncthreads();
            scan[t] = nv;
            __syncthreads();
        }
        int excl = scan[t] - own;
        if (t < 128) { exc0[t] = excl; cur0[t] = excl; }
        __syncthreads();
        for (int i = t; i < n2; i += 256) {
            unsigned w = ebuf[st2 + i];
            int pos = atomicAdd(&cur0[w >> 18], 1);
            S0[pos] = w & SMASK;
        }
        __syncthreads();
        // no write-back: rel2 sorted list has no downstream consumer
        float uw0 = uvec[32 + c2], uw1 = uvec[32 + c2 + 1];
        float br0 = b1l_r[c2], br1 = b1l_r[c2 + 1];
        for (int k = 0; k < 4; ++k) {
            int nd = sg * 4 + k;
            int ga = b * 64 + nd;
            if (ga >= NA) break;
            int nR = cnt0[nd];
            float2 aR = gatherL(YpR, S0, exc0[nd], nR, l16);
            float rR = 1.f / (float)max(nR, 1);
            bf16x2 d = *(const bf16x2*)(YaD + (size_t)ga * 32 + c2);
            float p0 = fmaxf(aR.x * rR + (float)d[0] + br0, 0.f);
            float p1 = fmaxf(aR.y * rR + (float)d[1] + br1, 0.f);
            float vw = p0 * uw0 + p1 * uw1;
            for (int m = 1; m < 16; m <<= 1) vw += __shfl_xor(vw, m, 64);
            if (l16 == 0) s_w[ga] = vw;
        }
    }
}

// ---------------- layer-2 scalar aggregation + output: lane per node -----------
__global__ __launch_bounds__(256) void out_kernel(
    const float* __restrict__ s_c, const float* __restrict__ s_w,
    const float* __restrict__ s_r, const unsigned* __restrict__ ebuf,
    const int* __restrict__ nstart, const int* __restrict__ ncnt,
    const float* __restrict__ uvec, float* __restrict__ out, int NP) {
    int gn = blockIdx.x * 256 + threadIdx.x;
    if (gn >= NP) return;
    const int NPS = NBKT * 128;
    int o = nstart[gn], n = ncnt[gn];
    float sC = 0.f;
    for (int e = 0; e < n; e += 4) {
        int m = n - e;
        int a0 = ebuf[o + e];
        int a1 = (m > 1) ? (int)ebuf[o + e + 1] : a0;
        int a2 = (m > 2) ? (int)ebuf[o + e + 2] : a0;
        int a3 = (m > 3) ? (int)ebuf[o + e + 3] : a0;
        float f0 = s_c[a0], f1 = s_c[a1], f2 = s_c[a2], f3 = s_c[a3];
        sC += f0;
        if (m > 1) sC += f1;
        if (m > 2) sC += f2;
        if (m > 3) sC += f3;
    }
    int o2 = nstart[NPS + gn], n2 = ncnt[NPS + gn];
    float sW = 0.f;
    for (int e = 0; e < n2; e += 4) {
        int m = n2 - e;
        int a0 = ebuf[o2 + e];
        int a1 = (m > 1) ? (int)ebuf[o2 + e + 1] : a0;
        int a2 = (m > 2) ? (int)ebuf[o2 + e + 2] : a0;
        int a3 = (m > 3) ? (int)ebuf[o2 + e + 3] : a0;
        float f0 = s_w[a0], f1 = s_w[a1], f2 = s_w[a2], f3 = s_w[a3];
        sW += f0;
        if (m > 1) sW += f1;
        if (m > 2) sW += f2;
        if (m > 3) sW += f3;
    }
    out[gn] = sC / (float)max(n, 1) + sW / (float)max(n2, 1) + s_r[gn] + uvec[96];
}

extern "C" void kernel_launch(void* const* d_in, const int* in_sizes, int n_in,
                              void* d_out, int out_size, void* d_ws, size_t ws_size,
                              hipStream_t stream) {
    const float* x_paper  = (const float*)d_in[0];
    const float* x_author = (const float*)d_in[1];
    const int* eiC = (const int*)d_in[2];
    const int* eiW = (const int*)d_in[3];
    const int* eiR = (const int*)d_in[4];
    const float* W1l_c  = (const float*)d_in[5];
    const float* b1l_c  = (const float*)d_in[6];
    const float* W1r_c  = (const float*)d_in[7];
    const float* W1l_w  = (const float*)d_in[8];
    const float* b1l_w  = (const float*)d_in[9];
    const float* W1r_w  = (const float*)d_in[10];
    const float* W1l_r  = (const float*)d_in[11];
    const float* b1l_r  = (const float*)d_in[12];
    const float* W1r_r  = (const float*)d_in[13];
    const float* W2l_c  = (const float*)d_in[14];
    const float* b2l_c  = (const float*)d_in[15];
    const float* W2r_c  = (const float*)d_in[16];
    const float* W2l_w  = (const float*)d_in[17];
    const float* b2l_w  = (const float*)d_in[18];
    const float* W2r_w  = (const float*)d_in[19];
    // d_in[20..22] unused (author layer-2 output not consumed)
    const float* Wh = (const float*)d_in[23];
    const float* bh = (const float*)d_in[24];

    const int NP = in_sizes[0] / 128;
    const int NA = in_sizes[1] / 64;
    const int E  = in_sizes[2] / 2;
    const int npart = (E + SPAN - 1) / SPAN;
    const int nPp = (NP + 63) / 64;
    const int nPa = (NA + 63) / 64;
    const int NNODE = NBKT * 128 * 2 + NBKT * 64;

    char* p = (char*)d_ws;
    auto alloc = [&](size_t bytes) -> void* {
        void* r = (void*)p;
        p += (bytes + 255) & ~(size_t)255;
        return r;
    };
    __bf16* YpC = (__bf16*)alloc((size_t)NP * 32 * 2);
    __bf16* YpR = (__bf16*)alloc((size_t)NP * 32 * 2);
    __bf16* YpD = (__bf16*)alloc((size_t)NP * 32 * 2);
    __bf16* YaW = (__bf16*)alloc((size_t)NA * 32 * 2);
    __bf16* YaD = (__bf16*)alloc((size_t)NA * 32 * 2);
    __bf16* Bp_t = (__bf16*)alloc(96 * 128 * 2);
    __bf16* Ba_t = (__bf16*)alloc(64 * 64 * 2);
    float* uvec = (float*)alloc(128 * 4);
    float* s_c  = (float*)alloc((size_t)NP * 4);
    float* s_r  = (float*)alloc((size_t)NP * 4);
    float* s_w  = (float*)alloc((size_t)NA * 4);
    int* gcur   = (int*)alloc((size_t)3 * NBKT * GPAD * 4);   // 300KB, 1 line/counter
    int* nstart = (int*)alloc((size_t)NNODE * 4);
    int* ncnt   = (int*)alloc((size_t)NNODE * 4);
    unsigned* ebuf = (unsigned*)alloc((size_t)3 * NBKT * CAP * 4);   // 19.2 MB

    prep_kernel<<<20, 256, 0, stream>>>(W1l_c, W1l_r, W1r_c, W1r_w, W1l_w, W1r_r,
                                        W2l_c, W2l_w, W2r_c, W2r_w, b2l_c, b2l_w,
                                        Wh, bh, Bp_t, Ba_t, uvec, gcur);

    mid_kernel<<<nPp + nPa + 3 * npart, 256, 0, stream>>>(
        x_paper, x_author, Bp_t, Ba_t, YpC, YpR, YpD, YaW, YaD,
        eiC, eiW, eiR, gcur, ebuf, NP, NA, E, nPp, nPa, npart);

    sagg_kernel<<<2 * NBKT, 256, 0, stream>>>(
        YpC, YaW, YpD, YpR, YaD, ebuf, gcur, nstart, ncnt,
        b1l_c, b1l_w, b1l_r, uvec, s_c, s_r, s_w, NP, NA);

    out_kernel<<<(NP + 255) / 256, 256, 0, stream>>>(
        s_c, s_w, s_r, ebuf, nstart, ncnt, uvec, (float*)d_out, NP);
}

// Round 11
// 374.948 us; speedup vs baseline: 1.1455x; 1.1455x over previous
//
#include <hip/hip_runtime.h>
#include <hip/hip_bf16.h>

// HeteroSAGE collapsed pipeline (float32 I/O, bf16 MFMA + bf16 intermediates):
//   out[i] = mean_cites(s_c[src]) + mean_writes(s_w[src]) + s_r[i] + C0
//   s_c = p1.(W2l_c@Wh), s_r = p1.((W2r_c+W2r_w)@Wh), s_w = a1.(W2l_w@Wh)
//   p1 = relu(mean_c(YpC[src]) + mean_w(YaW[src]) + YpD + b1c + b1w)
//   a1 = relu(mean_r(YpR[src]) + YaD + b1rev)
// R8: direct-claim scatter -> mid 143us. R9: SPAN 2048 -> mid 125us, occ 51%.
// R10: fused sort+agg (VERIFIED). R11-R13: LDS-atomic agg CONVICTED. R14:
// revert verified 397.5us. R15: prep grid-stride + gatherCW -> VERIFIED
// 377.6us. R16: gcur 64B-padding REFUTED (mid 128->182, WRITE +29MB). R17:
// cooperative sagg+out fusion CONVICTED on launch mechanics (absmax == ref
// max, first check, 2.5s: hipLaunchCooperativeKernel no-op'd under graph
// capture -> out never written). R18 (this round): R15 base + order-preserving
// MLP upgrades only: author gathers paired via gatherCW(YpR,YpR) (4->2 rounds,
// 8 loads in flight); paper loop paired (8->4 rounds, 16 loads in flight via
// two adjacent gatherCW calls); out_kernel 4->8-wide. Per-list accumulation
// order unchanged -> bit-identical. mid untouched.

#define SPAN  2048
#define EPT   8           // SPAN / 256 edges per thread
#define NBKT  1563        // ceil(200000/128) == ceil(100000/64)
#define CAP   1024        // padded region per (rel,bucket); Poisson(640), 15 sigma
#define SMASK 0x3FFFF     // 18-bit src index (200000 < 2^18)

typedef __bf16 bf16x8 __attribute__((ext_vector_type(8)));
typedef __bf16 bf16x2 __attribute__((ext_vector_type(2)));
typedef float f32x4 __attribute__((ext_vector_type(4)));

// ---------------- prep: weights -> bf16, head vecs, cursor init ----------------
// Grid-strided across blocks; only block 0 computes the 32-wide uvec collapse.
__global__ void prep_kernel(const float* W1l_c, const float* W1l_rev,
                            const float* W1r_c, const float* W1r_w,
                            const float* W1l_w, const float* W1r_rev,
                            const float* W2l_c, const float* W2l_w,
                            const float* W2r_c, const float* W2r_w,
                            const float* b2l_c, const float* b2l_w,
                            const float* Wh, const float* bh,
                            __bf16* Bp_t, __bf16* Ba_t, float* uvec, int* gcur) {
    int tid = blockIdx.x * 256 + threadIdx.x;
    int nthr = gridDim.x * 256;
    for (int i = tid; i < 3 * NBKT; i += nthr) gcur[i] = i << 10;   // padded bases
    for (int idx = tid; idx < 96 * 128; idx += nthr) {   // Bp_t[n][k] n<96,k<128
        int n = idx >> 7, k = idx & 127;
        float v;
        if (n < 32)      v = W1l_c[k * 32 + n];
        else if (n < 64) v = W1l_rev[k * 32 + (n - 32)];
        else             v = W1r_c[k * 32 + (n - 64)] + W1r_w[k * 32 + (n - 64)];
        Bp_t[n * 128 + k] = (__bf16)v;
    }
    for (int idx = tid; idx < 64 * 64; idx += nthr) {    // Ba_t[n][k] n<64,k<64
        int n = idx >> 6, k = idx & 63;
        float v = (n < 32) ? W1l_w[k * 32 + n] : W1r_rev[k * 32 + (n - 32)];
        Ba_t[n * 64 + k] = (__bf16)v;
    }
    if (blockIdx.x == 0 && threadIdx.x < 32) {
        int t = threadIdx.x;
        float uc = 0.f, uw = 0.f, ur = 0.f;
        for (int j = 0; j < 32; ++j) {
            float wh = Wh[j];
            uc += W2l_c[t * 32 + j] * wh;
            uw += W2l_w[t * 32 + j] * wh;
            ur += (W2r_c[t * 32 + j] + W2r_w[t * 32 + j]) * wh;
        }
        uvec[t] = uc; uvec[32 + t] = uw; uvec[64 + t] = ur;
        if (t == 0) {
            float c0 = bh[0];
            for (int j = 0; j < 32; ++j) c0 += (b2l_c[j] + b2l_w[j]) * Wh[j];
            uvec[96] = c0;
        }
    }
}

// ---------------- proj body (MFMA 16x16x32 bf16), 32-col group split -----------
template <int K, int NG>
__device__ __forceinline__ void proj_body(const float* __restrict__ X,
                                          const __bf16* __restrict__ Bt,
                                          __bf16* __restrict__ D0,
                                          __bf16* __restrict__ D1,
                                          __bf16* __restrict__ D2, int M, int bid) {
    constexpr int NT = NG * 2, KT = K / 32;
    int lane = threadIdx.x & 63;
    int wave = (bid * 256 + (int)threadIdx.x) >> 6;
    int m0 = wave * 16;
    if (m0 + 16 > M) return;  // M % 16 == 0 here
    int lr = lane & 15;
    int quad = lane >> 4;

    bf16x8 bfrag[NT][KT];
#pragma unroll
    for (int ct = 0; ct < NT; ++ct)
#pragma unroll
        for (int ks = 0; ks < KT; ++ks)
            bfrag[ct][ks] = *(const bf16x8*)(Bt + (ct * 16 + lr) * K + ks * 32 + quad * 8);

    bf16x8 afrag[KT];
    const float* xrow = X + (size_t)(m0 + lr) * K + quad * 8;
#pragma unroll
    for (int ks = 0; ks < KT; ++ks) {
        f32x4 lo = *(const f32x4*)(xrow + ks * 32);
        f32x4 hi = *(const f32x4*)(xrow + ks * 32 + 4);
        bf16x8 a;
#pragma unroll
        for (int j = 0; j < 4; ++j) { a[j] = (__bf16)lo[j]; a[4 + j] = (__bf16)hi[j]; }
        afrag[ks] = a;
    }

    int odd = lane & 1;
#pragma unroll
    for (int ct = 0; ct < NT; ++ct) {
        f32x4 acc = {0.f, 0.f, 0.f, 0.f};
#pragma unroll
        for (int ks = 0; ks < KT; ++ks)
            acc = __builtin_amdgcn_mfma_f32_16x16x32_bf16(afrag[ks], bfrag[ct][ks], acc, 0, 0, 0);
        __bf16* D = ((ct >> 1) == 0) ? D0 : (((ct >> 1) == 1) ? D1 : D2);
        int col = (ct & 1) * 16 + lr;
        int cw = col & ~1;                 // even col of the lane pair
        int rbase = m0 + quad * 4;
        float o0 = __shfl_xor(acc[0], 1, 64);
        float o1 = __shfl_xor(acc[1], 1, 64);
        float o2 = __shfl_xor(acc[2], 1, 64);
        float o3 = __shfl_xor(acc[3], 1, 64);
        float s0 = odd ? o2 : acc[0], t0 = odd ? acc[2] : o0;   // row rb+0
        float s1 = odd ? o3 : acc[1], t1 = odd ? acc[3] : o1;   // row rb+1
        int rb = rbase + odd * 2;
        bf16x2 v0; v0[0] = (__bf16)s0; v0[1] = (__bf16)t0;
        bf16x2 v1; v1[0] = (__bf16)s1; v1[1] = (__bf16)t1;
        *(bf16x2*)(D + (size_t)(rb + 0) * 32 + cw) = v0;
        *(bf16x2*)(D + (size_t)(rb + 1) * 32 + cw) = v1;
    }
}

// ---------------- scatter body: direct-claim, arrival-order bucket fill --------
__device__ void scatter_body(const int* __restrict__ eiC, const int* __restrict__ eiW,
                             const int* __restrict__ eiR, int* __restrict__ gcur,
                             unsigned* __restrict__ ebuf, int E, int npart, int bid,
                             int* cnt) {
    int rel = bid / npart, blk = bid % npart;
    const int* ei = rel == 0 ? eiC : (rel == 1 ? eiW : eiR);
    int shift = (rel == 2) ? 6 : 7;
    unsigned dmask = (1u << shift) - 1;
    int t = threadIdx.x;
    int e0 = blk * SPAN, e1 = min(E, e0 + SPAN);
    for (int i = t; i < NBKT; i += 256) cnt[i] = 0;
    __syncthreads();
    int d8[EPT], s8[EPT];
#pragma unroll
    for (int j = 0; j < EPT; ++j) {
        int e = e0 + t + j * 256;
        if (e < e1) {
            d8[j] = ei[E + e];
            s8[j] = ei[e];
            atomicAdd(&cnt[d8[j] >> shift], 1);
        } else {
            d8[j] = -1;
        }
    }
    __syncthreads();
    for (int i = t; i < NBKT; i += 256) {
        int c = cnt[i];
        cnt[i] = c ? atomicAdd(&gcur[rel * NBKT + i], c) : 0;
    }
    __syncthreads();
#pragma unroll
    for (int j = 0; j < EPT; ++j) {
        if (d8[j] >= 0) {
            int b = d8[j] >> shift;
            int gpos = atomicAdd(&cnt[b], 1);
            if (gpos < (((rel * NBKT + b) + 1) << 10))   // capacity clamp (~never)
                ebuf[gpos] = ((unsigned)(d8[j] & dmask) << 18) | (unsigned)s8[j];
        }
    }
}

// ---------------- mid: scatter FIRST (long pole), then proj blocks -------------
__global__ __launch_bounds__(256) void mid_kernel(
    const float* __restrict__ Xp, const float* __restrict__ Xa,
    const __bf16* __restrict__ Bp_t, const __bf16* __restrict__ Ba_t,
    __bf16* __restrict__ YpC, __bf16* __restrict__ YpR, __bf16* __restrict__ YpD,
    __bf16* __restrict__ YaW, __bf16* __restrict__ YaD,
    const int* __restrict__ eiC, const int* __restrict__ eiW,
    const int* __restrict__ eiR, int* __restrict__ gcur,
    unsigned* __restrict__ ebuf, int NP, int NA, int E,
    int nPp, int nPa, int npart) {
    __shared__ int cnt[NBKT];     // 6.25 KB -> wave-limited occupancy, not LDS
    int bid = blockIdx.x;
    if (bid < 3 * npart) {
        scatter_body(eiC, eiW, eiR, gcur, ebuf, E, npart, bid, cnt);
        return;
    }
    bid -= 3 * npart;
    if (bid < nPp) { proj_body<128, 3>(Xp, Bp_t, YpC, YpR, YpD, NP, bid); return; }
    bid -= nPp;
    proj_body<64, 2>(Xa, Ba_t, YaW, YaD, nullptr, NA, bid);
}

// ---------------- merged dual gather: 8 independent Y-row loads in flight ------
// Two independent (list, Y) pairs; per-list accumulation order matches the
// original 4-wide gatherL -> bit-identical results. Short/empty lists fall
// back to index 0 (always a valid Y row); accumulation is predicate-guarded.
__device__ __forceinline__ void gatherCW(const __bf16* __restrict__ YA,
                                         const __bf16* __restrict__ YB,
                                         const unsigned* __restrict__ LA,
                                         const unsigned* __restrict__ LB,
                                         int oA, int nA, int oB, int nB, int l16,
                                         float2& rA, float2& rB) {
    float xA = 0.f, yA = 0.f, xB = 0.f, yB = 0.f;
    int nm = max(nA, nB);
    for (int e = 0; e < nm; e += 4) {
        unsigned a0 = (e + 0 < nA) ? LA[oA + e + 0] : 0u;
        unsigned a1 = (e + 1 < nA) ? LA[oA + e + 1] : 0u;
        unsigned a2 = (e + 2 < nA) ? LA[oA + e + 2] : 0u;
        unsigned a3 = (e + 3 < nA) ? LA[oA + e + 3] : 0u;
        unsigned b0 = (e + 0 < nB) ? LB[oB + e + 0] : 0u;
        unsigned b1 = (e + 1 < nB) ? LB[oB + e + 1] : 0u;
        unsigned b2 = (e + 2 < nB) ? LB[oB + e + 2] : 0u;
        unsigned b3 = (e + 3 < nB) ? LB[oB + e + 3] : 0u;
        bf16x2 vA0 = *(const bf16x2*)(YA + (size_t)a0 * 32 + 2 * l16);
        bf16x2 vA1 = *(const bf16x2*)(YA + (size_t)a1 * 32 + 2 * l16);
        bf16x2 vA2 = *(const bf16x2*)(YA + (size_t)a2 * 32 + 2 * l16);
        bf16x2 vA3 = *(const bf16x2*)(YA + (size_t)a3 * 32 + 2 * l16);
        bf16x2 vB0 = *(const bf16x2*)(YB + (size_t)b0 * 32 + 2 * l16);
        bf16x2 vB1 = *(const bf16x2*)(YB + (size_t)b1 * 32 + 2 * l16);
        bf16x2 vB2 = *(const bf16x2*)(YB + (size_t)b2 * 32 + 2 * l16);
        bf16x2 vB3 = *(const bf16x2*)(YB + (size_t)b3 * 32 + 2 * l16);
        if (e + 0 < nA) { xA += (float)vA0[0]; yA += (float)vA0[1]; }
        if (e + 1 < nA) { xA += (float)vA1[0]; yA += (float)vA1[1]; }
        if (e + 2 < nA) { xA += (float)vA2[0]; yA += (float)vA2[1]; }
        if (e + 3 < nA) { xA += (float)vA3[0]; yA += (float)vA3[1]; }
        if (e + 0 < nB) { xB += (float)vB0[0]; yB += (float)vB0[1]; }
        if (e + 1 < nB) { xB += (float)vB1[0]; yB += (float)vB1[1]; }
        if (e + 2 < nB) { xB += (float)vB2[0]; yB += (float)vB2[1]; }
        if (e + 3 < nB) { xB += (float)vB3[0]; yB += (float)vB3[1]; }
    }
    rA = make_float2(xA, yA);
    rB = make_float2(xB, yB);
}

// ---------------- sagg: fused per-bucket sort + aggregate + collapse -----------
// blocks [0,NBKT): paper bucket b (rel0 cites + rel1 writes), 128 nodes.
// blocks [NBKT,2*NBKT): author bucket b (rel2), 64 nodes, no write-back.
__global__ __launch_bounds__(256) void sagg_kernel(
    const __bf16* __restrict__ YpC, const __bf16* __restrict__ YaW,
    const __bf16* __restrict__ YpD, const __bf16* __restrict__ YpR,
    const __bf16* __restrict__ YaD, unsigned* __restrict__ ebuf,
    const int* __restrict__ gcur, int* __restrict__ nstart, int* __restrict__ ncnt,
    const float* __restrict__ b1l_c, const float* __restrict__ b1l_w,
    const float* __restrict__ b1l_r, const float* __restrict__ uvec,
    float* __restrict__ s_c, float* __restrict__ s_r, float* __restrict__ s_w,
    int NP, int NA) {
    __shared__ unsigned S0[CAP], S1[CAP];
    __shared__ int cnt0[128], exc0[128], cur0[128];
    __shared__ int cnt1[128], exc1[128], cur1[128];
    __shared__ int scan[256];
    const int NPS = NBKT * 128;
    int t = threadIdx.x;
    int sg = t >> 4, l16 = t & 15, c2 = 2 * l16;
    int bid = blockIdx.x;

    if (bid < NBKT) {
        // ---------------- papers ----------------
        int b = bid;
        int i0 = b, i1 = NBKT + b;
        int st0 = i0 << 10, st1 = i1 << 10;
        int n0 = min(gcur[i0] - st0, CAP), n1 = min(gcur[i1] - st1, CAP);
        if (t < 128) { cnt0[t] = 0; cnt1[t] = 0; }
        __syncthreads();
        for (int i = t; i < n0; i += 256) atomicAdd(&cnt0[ebuf[st0 + i] >> 18], 1);
        for (int i = t; i < n1; i += 256) atomicAdd(&cnt1[ebuf[st1 + i] >> 18], 1);
        __syncthreads();
        // dual 128-wide exclusive scan with 256 threads
        int own = (t < 128) ? cnt0[t] : cnt1[t - 128];
        scan[t] = own;
        __syncthreads();
        for (int d = 1; d < 128; d <<= 1) {
            int nv = scan[t] + (((t & 127) >= d) ? scan[t - d] : 0);
            __syncthreads();
            scan[t] = nv;
            __syncthreads();
        }
        int excl = scan[t] - own;
        if (t < 128) { exc0[t] = excl; cur0[t] = excl; }
        else         { exc1[t - 128] = excl; cur1[t - 128] = excl; }
        __syncthreads();
        // scatter into sorted LDS lists (plain src)
        for (int i = t; i < n0; i += 256) {
            unsigned w = ebuf[st0 + i];
            int pos = atomicAdd(&cur0[w >> 18], 1);
            S0[pos] = w & SMASK;
        }
        for (int i = t; i < n1; i += 256) {
            unsigned w = ebuf[st1 + i];
            int pos = atomicAdd(&cur1[w >> 18], 1);
            S1[pos] = w & SMASK;
        }
        __syncthreads();
        // fire-and-forget write-back for out_kernel (sorted lists + offsets)
        for (int i = t; i < n0; i += 256) ebuf[st0 + i] = S0[i];
        for (int i = t; i < n1; i += 256) ebuf[st1 + i] = S1[i];
        if (t < 128) {
            nstart[b * 128 + t] = st0 + exc0[t];
            ncnt[b * 128 + t] = cnt0[t];
            nstart[NPS + b * 128 + t] = st1 + exc1[t];
            ncnt[NPS + b * 128 + t] = cnt1[t];
        }
        // gather+combine: subgroup sg owns nodes sg*8 .. sg*8+7, paired
        float u0 = uvec[c2], u1 = uvec[c2 + 1];
        float w0 = uvec[64 + c2], w1 = uvec[64 + c2 + 1];
        float bc0 = b1l_c[c2] + b1l_w[c2], bc1 = b1l_c[c2 + 1] + b1l_w[c2 + 1];
        for (int k = 0; k < 4; ++k) {
            int nd = sg * 8 + 2 * k;
            int g = b * 128 + nd;
            if (g >= NP) break;                 // uniform in 16-lane group
            int nd2 = nd + 1, g2 = g + 1;
            bool v2 = (g2 < NP);                // uniform in 16-lane group
            int nC = cnt0[nd], nW = cnt1[nd];
            int nC2 = v2 ? cnt0[nd2] : 0, nW2 = v2 ? cnt1[nd2] : 0;
            float2 aC, aW, aC2, aW2;
            gatherCW(YpC, YaW, S0, S1, exc0[nd], nC, exc1[nd], nW, l16, aC, aW);
            gatherCW(YpC, YaW, S0, S1, exc0[nd2], nC2, exc1[nd2], nW2, l16, aC2, aW2);
            float rC = 1.f / (float)max(nC, 1), rW = 1.f / (float)max(nW, 1);
            bf16x2 d = *(const bf16x2*)(YpD + (size_t)g * 32 + c2);
            float p0 = fmaxf(aC.x * rC + aW.x * rW + (float)d[0] + bc0, 0.f);
            float p1 = fmaxf(aC.y * rC + aW.y * rW + (float)d[1] + bc1, 0.f);
            float vc = p0 * u0 + p1 * u1;
            float vr = p0 * w0 + p1 * w1;
            float vc2 = 0.f, vr2 = 0.f;
            if (v2) {
                float rC2 = 1.f / (float)max(nC2, 1), rW2 = 1.f / (float)max(nW2, 1);
                bf16x2 d2 = *(const bf16x2*)(YpD + (size_t)g2 * 32 + c2);
                float q0 = fmaxf(aC2.x * rC2 + aW2.x * rW2 + (float)d2[0] + bc0, 0.f);
                float q1 = fmaxf(aC2.y * rC2 + aW2.y * rW2 + (float)d2[1] + bc1, 0.f);
                vc2 = q0 * u0 + q1 * u1;
                vr2 = q0 * w0 + q1 * w1;
            }
            for (int m = 1; m < 16; m <<= 1) {
                vc += __shfl_xor(vc, m, 64);  vr += __shfl_xor(vr, m, 64);
                vc2 += __shfl_xor(vc2, m, 64); vr2 += __shfl_xor(vr2, m, 64);
            }
            if (l16 == 0) {
                s_c[g] = vc; s_r[g] = vr;
                if (v2) { s_c[g2] = vc2; s_r[g2] = vr2; }
            }
        }
    } else {
        // ---------------- authors ----------------
        int b = bid - NBKT;
        int i2 = 2 * NBKT + b;
        int st2 = i2 << 10;
        int n2 = min(gcur[i2] - st2, CAP);
        if (t < 128) { cnt0[t] = 0; cnt1[t] = 0; }
        __syncthreads();
        for (int i = t; i < n2; i += 256) atomicAdd(&cnt0[ebuf[st2 + i] >> 18], 1);
        __syncthreads();
        int own = (t < 128) ? cnt0[t] : 0;
        scan[t] = own;
        __syncthreads();
        for (int d = 1; d < 128; d <<= 1) {
            int nv = scan[t] + (((t & 127) >= d) ? scan[t - d] : 0);
            __syncthreads();
            scan[t] = nv;
            __syncthreads();
        }
        int excl = scan[t] - own;
        if (t < 128) { exc0[t] = excl; cur0[t] = excl; }
        __syncthreads();
        for (int i = t; i < n2; i += 256) {
            unsigned w = ebuf[st2 + i];
            int pos = atomicAdd(&cur0[w >> 18], 1);
            S0[pos] = w & SMASK;
        }
        __syncthreads();
        // no write-back: rel2 sorted list has no downstream consumer
        float uw0 = uvec[32 + c2], uw1 = uvec[32 + c2 + 1];
        float br0 = b1l_r[c2], br1 = b1l_r[c2 + 1];
        for (int k = 0; k < 2; ++k) {
            int nd = sg * 4 + 2 * k;
            int ga = b * 64 + nd;
            if (ga >= NA) break;                // uniform in 16-lane group
            int nd2 = nd + 1, ga2 = ga + 1;
            bool v2 = (ga2 < NA);               // uniform in 16-lane group
            int nR = cnt0[nd], nR2 = v2 ? cnt0[nd2] : 0;
            float2 aR, aR2;
            gatherCW(YpR, YpR, S0, S0, exc0[nd], nR, exc0[nd2], nR2, l16, aR, aR2);
            float rR = 1.f / (float)max(nR, 1);
            bf16x2 d = *(const bf16x2*)(YaD + (size_t)ga * 32 + c2);
            float p0 = fmaxf(aR.x * rR + (float)d[0] + br0, 0.f);
            float p1 = fmaxf(aR.y * rR + (float)d[1] + br1, 0.f);
            float vw = p0 * uw0 + p1 * uw1;
            float vw2 = 0.f;
            if (v2) {
                float rR2 = 1.f / (float)max(nR2, 1);
                bf16x2 d2 = *(const bf16x2*)(YaD + (size_t)ga2 * 32 + c2);
                float q0 = fmaxf(aR2.x * rR2 + (float)d2[0] + br0, 0.f);
                float q1 = fmaxf(aR2.y * rR2 + (float)d2[1] + br1, 0.f);
                vw2 = q0 * uw0 + q1 * uw1;
            }
            for (int m = 1; m < 16; m <<= 1) {
                vw += __shfl_xor(vw, m, 64); vw2 += __shfl_xor(vw2, m, 64);
            }
            if (l16 == 0) {
                s_w[ga] = vw;
                if (v2) s_w[ga2] = vw2;
            }
        }
    }
}

// ---------------- layer-2 scalar aggregation + output: lane per node -----------
__global__ __launch_bounds__(256) void out_kernel(
    const float* __restrict__ s_c, const float* __restrict__ s_w,
    const float* __restrict__ s_r, const unsigned* __restrict__ ebuf,
    const int* __restrict__ nstart, const int* __restrict__ ncnt,
    const float* __restrict__ uvec, float* __restrict__ out, int NP) {
    int gn = blockIdx.x * 256 + threadIdx.x;
    if (gn >= NP) return;
    const int NPS = NBKT * 128;
    int o = nstart[gn], n = ncnt[gn];
    float sC = 0.f;
    for (int e = 0; e < n; e += 8) {
        int m = n - e;
        int a0 = ebuf[o + e];
        int a1 = (m > 1) ? (int)ebuf[o + e + 1] : a0;
        int a2 = (m > 2) ? (int)ebuf[o + e + 2] : a0;
        int a3 = (m > 3) ? (int)ebuf[o + e + 3] : a0;
        int a4 = (m > 4) ? (int)ebuf[o + e + 4] : a0;
        int a5 = (m > 5) ? (int)ebuf[o + e + 5] : a0;
        int a6 = (m > 6) ? (int)ebuf[o + e + 6] : a0;
        int a7 = (m > 7) ? (int)ebuf[o + e + 7] : a0;
        float f0 = s_c[a0], f1 = s_c[a1], f2 = s_c[a2], f3 = s_c[a3];
        float f4 = s_c[a4], f5 = s_c[a5], f6 = s_c[a6], f7 = s_c[a7];
        sC += f0;
        if (m > 1) sC += f1;
        if (m > 2) sC += f2;
        if (m > 3) sC += f3;
        if (m > 4) sC += f4;
        if (m > 5) sC += f5;
        if (m > 6) sC += f6;
        if (m > 7) sC += f7;
    }
    int o2 = nstart[NPS + gn], n2 = ncnt[NPS + gn];
    float sW = 0.f;
    for (int e = 0; e < n2; e += 8) {
        int m = n2 - e;
        int a0 = ebuf[o2 + e];
        int a1 = (m > 1) ? (int)ebuf[o2 + e + 1] : a0;
        int a2 = (m > 2) ? (int)ebuf[o2 + e + 2] : a0;
        int a3 = (m > 3) ? (int)ebuf[o2 + e + 3] : a0;
        int a4 = (m > 4) ? (int)ebuf[o2 + e + 4] : a0;
        int a5 = (m > 5) ? (int)ebuf[o2 + e + 5] : a0;
        int a6 = (m > 6) ? (int)ebuf[o2 + e + 6] : a0;
        int a7 = (m > 7) ? (int)ebuf[o2 + e + 7] : a0;
        float f0 = s_w[a0], f1 = s_w[a1], f2 = s_w[a2], f3 = s_w[a3];
        float f4 = s_w[a4], f5 = s_w[a5], f6 = s_w[a6], f7 = s_w[a7];
        sW += f0;
        if (m > 1) sW += f1;
        if (m > 2) sW += f2;
        if (m > 3) sW += f3;
        if (m > 4) sW += f4;
        if (m > 5) sW += f5;
        if (m > 6) sW += f6;
        if (m > 7) sW += f7;
    }
    out[gn] = sC / (float)max(n, 1) + sW / (float)max(n2, 1) + s_r[gn] + uvec[96];
}

extern "C" void kernel_launch(void* const* d_in, const int* in_sizes, int n_in,
                              void* d_out, int out_size, void* d_ws, size_t ws_size,
                              hipStream_t stream) {
    const float* x_paper  = (const float*)d_in[0];
    const float* x_author = (const float*)d_in[1];
    const int* eiC = (const int*)d_in[2];
    const int* eiW = (const int*)d_in[3];
    const int* eiR = (const int*)d_in[4];
    const float* W1l_c  = (const float*)d_in[5];
    const float* b1l_c  = (const float*)d_in[6];
    const float* W1r_c  = (const float*)d_in[7];
    const float* W1l_w  = (const float*)d_in[8];
    const float* b1l_w  = (const float*)d_in[9];
    const float* W1r_w  = (const float*)d_in[10];
    const float* W1l_r  = (const float*)d_in[11];
    const float* b1l_r  = (const float*)d_in[12];
    const float* W1r_r  = (const float*)d_in[13];
    const float* W2l_c  = (const float*)d_in[14];
    const float* b2l_c  = (const float*)d_in[15];
    const float* W2r_c  = (const float*)d_in[16];
    const float* W2l_w  = (const float*)d_in[17];
    const float* b2l_w  = (const float*)d_in[18];
    const float* W2r_w  = (const float*)d_in[19];
    // d_in[20..22] unused (author layer-2 output not consumed)
    const float* Wh = (const float*)d_in[23];
    const float* bh = (const float*)d_in[24];

    const int NP = in_sizes[0] / 128;
    const int NA = in_sizes[1] / 64;
    const int E  = in_sizes[2] / 2;
    const int npart = (E + SPAN - 1) / SPAN;
    const int nPp = (NP + 63) / 64;
    const int nPa = (NA + 63) / 64;
    const int NNODE = NBKT * 128 * 2 + NBKT * 64;

    char* p = (char*)d_ws;
    auto alloc = [&](size_t bytes) -> void* {
        void* r = (void*)p;
        p += (bytes + 255) & ~(size_t)255;
        return r;
    };
    __bf16* YpC = (__bf16*)alloc((size_t)NP * 32 * 2);
    __bf16* YpR = (__bf16*)alloc((size_t)NP * 32 * 2);
    __bf16* YpD = (__bf16*)alloc((size_t)NP * 32 * 2);
    __bf16* YaW = (__bf16*)alloc((size_t)NA * 32 * 2);
    __bf16* YaD = (__bf16*)alloc((size_t)NA * 32 * 2);
    __bf16* Bp_t = (__bf16*)alloc(96 * 128 * 2);
    __bf16* Ba_t = (__bf16*)alloc(64 * 64 * 2);
    float* uvec = (float*)alloc(128 * 4);
    float* s_c  = (float*)alloc((size_t)NP * 4);
    float* s_r  = (float*)alloc((size_t)NP * 4);
    float* s_w  = (float*)alloc((size_t)NA * 4);
    int* gcur   = (int*)alloc((size_t)3 * NBKT * 4);
    int* nstart = (int*)alloc((size_t)NNODE * 4);
    int* ncnt   = (int*)alloc((size_t)NNODE * 4);
    unsigned* ebuf = (unsigned*)alloc((size_t)3 * NBKT * CAP * 4);   // 19.2 MB

    prep_kernel<<<20, 256, 0, stream>>>(W1l_c, W1l_r, W1r_c, W1r_w, W1l_w, W1r_r,
                                        W2l_c, W2l_w, W2r_c, W2r_w, b2l_c, b2l_w,
                                        Wh, bh, Bp_t, Ba_t, uvec, gcur);

    mid_kernel<<<nPp + nPa + 3 * npart, 256, 0, stream>>>(
        x_paper, x_author, Bp_t, Ba_t, YpC, YpR, YpD, YaW, YaD,
        eiC, eiW, eiR, gcur, ebuf, NP, NA, E, nPp, nPa, npart);

    sagg_kernel<<<2 * NBKT, 256, 0, stream>>>(
        YpC, YaW, YpD, YpR, YaD, ebuf, gcur, nstart, ncnt,
        b1l_c, b1l_w, b1l_r, uvec, s_c, s_r, s_w, NP, NA);

    out_kernel<<<(NP + 255) / 256, 256, 0, stream>>>(
        s_c, s_w, s_r, ebuf, nstart, ncnt, uvec, (float*)d_out, NP);
}

// Round 12
// 364.412 us; speedup vs baseline: 1.1787x; 1.0289x over previous
//
#include <hip/hip_runtime.h>
#include <hip/hip_bf16.h>

// HeteroSAGE collapsed pipeline (float32 I/O, bf16 MFMA + bf16 intermediates):
//   out[i] = mean_cites(s_c[src]) + mean_writes(s_w[src]) + s_r[i] + C0
//   s_c = p1.(W2l_c@Wh), s_r = p1.((W2r_c+W2r_w)@Wh), s_w = a1.(W2l_w@Wh)
//   p1 = relu(mean_c(YpC[src]) + mean_w(YaW[src]) + YpD + b1c + b1w)
//   a1 = relu(mean_r(YpR[src]) + YaD + b1rev)
// R8: direct-claim scatter -> mid 143us. R9: SPAN 2048 -> mid 125us, occ 51%.
// R10: fused sort+agg (VERIFIED). R11-R13: LDS-atomic agg CONVICTED. R14:
// revert verified 397.5. R15: prep grid-stride + gatherCW -> VERIFIED 377.6.
// R16: gcur line-padding REFUTED (tested layout, not count). R17: cooperative
// fusion CONVICTED (launch no-op under capture). R18: gather-MLP pairing NULL
// (-2.7us) -> sagg gathers exonerated; top-5 shows sagg/out all <124us.
// R19 (this round): test the claim-COUNT/chain theory surgically -- pack two
// adjacent buckets' intra-region cursors into one u32 (16-bit fields; counts
// <=~800 so no field carry; packed atomicAdd returns exact per-field prefix).
// Claims drop ~1.6x, dependent claim-chain halves (782 words), zero-loop
// halves, mid LDS 6.6->3.3KB. Hist/write-pass use packed fields too (same
// atomic count; ebuf contents identical up to intra-bucket order, re-sorted
// in sagg). Loads split from atomics so 16 edge loads are in flight first.

#define SPAN  2048
#define EPT   8           // SPAN / 256 edges per thread
#define NBKT  1563        // ceil(200000/128) == ceil(100000/64)
#define NPAIR 782         // ceil(NBKT/2) packed cursor words per relation
#define CAP   1024        // padded region per (rel,bucket); Poisson(640), 15 sigma
#define SMASK 0x3FFFF     // 18-bit src index (200000 < 2^18)

typedef __bf16 bf16x8 __attribute__((ext_vector_type(8)));
typedef __bf16 bf16x2 __attribute__((ext_vector_type(2)));
typedef float f32x4 __attribute__((ext_vector_type(4)));

// ---------------- prep: weights -> bf16, head vecs, cursor init ----------------
// Grid-strided across blocks; only block 0 computes the 32-wide uvec collapse.
__global__ void prep_kernel(const float* W1l_c, const float* W1l_rev,
                            const float* W1r_c, const float* W1r_w,
                            const float* W1l_w, const float* W1r_rev,
                            const float* W2l_c, const float* W2l_w,
                            const float* W2r_c, const float* W2r_w,
                            const float* b2l_c, const float* b2l_w,
                            const float* Wh, const float* bh,
                            __bf16* Bp_t, __bf16* Ba_t, float* uvec,
                            unsigned* gcur) {
    int tid = blockIdx.x * 256 + threadIdx.x;
    int nthr = gridDim.x * 256;
    for (int i = tid; i < 3 * NPAIR; i += nthr) gcur[i] = 0u;  // packed intra-lens
    for (int idx = tid; idx < 96 * 128; idx += nthr) {   // Bp_t[n][k] n<96,k<128
        int n = idx >> 7, k = idx & 127;
        float v;
        if (n < 32)      v = W1l_c[k * 32 + n];
        else if (n < 64) v = W1l_rev[k * 32 + (n - 32)];
        else             v = W1r_c[k * 32 + (n - 64)] + W1r_w[k * 32 + (n - 64)];
        Bp_t[n * 128 + k] = (__bf16)v;
    }
    for (int idx = tid; idx < 64 * 64; idx += nthr) {    // Ba_t[n][k] n<64,k<64
        int n = idx >> 6, k = idx & 63;
        float v = (n < 32) ? W1l_w[k * 32 + n] : W1r_rev[k * 32 + (n - 32)];
        Ba_t[n * 64 + k] = (__bf16)v;
    }
    if (blockIdx.x == 0 && threadIdx.x < 32) {
        int t = threadIdx.x;
        float uc = 0.f, uw = 0.f, ur = 0.f;
        for (int j = 0; j < 32; ++j) {
            float wh = Wh[j];
            uc += W2l_c[t * 32 + j] * wh;
            uw += W2l_w[t * 32 + j] * wh;
            ur += (W2r_c[t * 32 + j] + W2r_w[t * 32 + j]) * wh;
        }
        uvec[t] = uc; uvec[32 + t] = uw; uvec[64 + t] = ur;
        if (t == 0) {
            float c0 = bh[0];
            for (int j = 0; j < 32; ++j) c0 += (b2l_c[j] + b2l_w[j]) * Wh[j];
            uvec[96] = c0;
        }
    }
}

// ---------------- proj body (MFMA 16x16x32 bf16), 32-col group split -----------
template <int K, int NG>
__device__ __forceinline__ void proj_body(const float* __restrict__ X,
                                          const __bf16* __restrict__ Bt,
                                          __bf16* __restrict__ D0,
                                          __bf16* __restrict__ D1,
                                          __bf16* __restrict__ D2, int M, int bid) {
    constexpr int NT = NG * 2, KT = K / 32;
    int lane = threadIdx.x & 63;
    int wave = (bid * 256 + (int)threadIdx.x) >> 6;
    int m0 = wave * 16;
    if (m0 + 16 > M) return;  // M % 16 == 0 here
    int lr = lane & 15;
    int quad = lane >> 4;

    bf16x8 bfrag[NT][KT];
#pragma unroll
    for (int ct = 0; ct < NT; ++ct)
#pragma unroll
        for (int ks = 0; ks < KT; ++ks)
            bfrag[ct][ks] = *(const bf16x8*)(Bt + (ct * 16 + lr) * K + ks * 32 + quad * 8);

    bf16x8 afrag[KT];
    const float* xrow = X + (size_t)(m0 + lr) * K + quad * 8;
#pragma unroll
    for (int ks = 0; ks < KT; ++ks) {
        f32x4 lo = *(const f32x4*)(xrow + ks * 32);
        f32x4 hi = *(const f32x4*)(xrow + ks * 32 + 4);
        bf16x8 a;
#pragma unroll
        for (int j = 0; j < 4; ++j) { a[j] = (__bf16)lo[j]; a[4 + j] = (__bf16)hi[j]; }
        afrag[ks] = a;
    }

    int odd = lane & 1;
#pragma unroll
    for (int ct = 0; ct < NT; ++ct) {
        f32x4 acc = {0.f, 0.f, 0.f, 0.f};
#pragma unroll
        for (int ks = 0; ks < KT; ++ks)
            acc = __builtin_amdgcn_mfma_f32_16x16x32_bf16(afrag[ks], bfrag[ct][ks], acc, 0, 0, 0);
        __bf16* D = ((ct >> 1) == 0) ? D0 : (((ct >> 1) == 1) ? D1 : D2);
        int col = (ct & 1) * 16 + lr;
        int cw = col & ~1;                 // even col of the lane pair
        int rbase = m0 + quad * 4;
        float o0 = __shfl_xor(acc[0], 1, 64);
        float o1 = __shfl_xor(acc[1], 1, 64);
        float o2 = __shfl_xor(acc[2], 1, 64);
        float o3 = __shfl_xor(acc[3], 1, 64);
        float s0 = odd ? o2 : acc[0], t0 = odd ? acc[2] : o0;   // row rb+0
        float s1 = odd ? o3 : acc[1], t1 = odd ? acc[3] : o1;   // row rb+1
        int rb = rbase + odd * 2;
        bf16x2 v0; v0[0] = (__bf16)s0; v0[1] = (__bf16)t0;
        bf16x2 v1; v1[0] = (__bf16)s1; v1[1] = (__bf16)t1;
        *(bf16x2*)(D + (size_t)(rb + 0) * 32 + cw) = v0;
        *(bf16x2*)(D + (size_t)(rb + 1) * 32 + cw) = v1;
    }
}

// ------ scatter body: packed-pair direct-claim, arrival-order bucket fill ------
// gcur[rel*NPAIR + (b>>1)] holds two 16-bit intra-region cursors. Counts per
// bucket <= ~800 << 2^16, so packed atomicAdd never carries across fields and
// the returned old value gives exact per-field prefix sums.
__device__ void scatter_body(const int* __restrict__ eiC, const int* __restrict__ eiW,
                             const int* __restrict__ eiR, unsigned* __restrict__ gcur,
                             unsigned* __restrict__ ebuf, int E, int npart, int bid,
                             unsigned* cnt) {
    int rel = bid / npart, blk = bid % npart;
    const int* ei = rel == 0 ? eiC : (rel == 1 ? eiW : eiR);
    int shift = (rel == 2) ? 6 : 7;
    unsigned dmask = (1u << shift) - 1;
    int t = threadIdx.x;
    int e0 = blk * SPAN, e1 = min(E, e0 + SPAN);
    for (int i = t; i < NPAIR; i += 256) cnt[i] = 0u;
    __syncthreads();
    int d8[EPT], s8[EPT];
#pragma unroll
    for (int j = 0; j < EPT; ++j) {       // all 16 loads in flight first
        int e = e0 + t + j * 256;
        d8[j] = (e < e1) ? ei[E + e] : -1;
        s8[j] = (e < e1) ? ei[e] : 0;
    }
#pragma unroll
    for (int j = 0; j < EPT; ++j) {       // packed hist
        if (d8[j] >= 0) {
            int b = d8[j] >> shift;
            atomicAdd(&cnt[b >> 1], 1u << ((b & 1) * 16));
        }
    }
    __syncthreads();
    // packed claim: one global atomic per non-empty PAIR; old -> per-field base
    unsigned* gp = gcur + rel * NPAIR;
    for (int i = t; i < NPAIR; i += 256) {
        unsigned c = cnt[i];
        cnt[i] = c ? atomicAdd(&gp[i], c) : 0u;
    }
    __syncthreads();
#pragma unroll
    for (int j = 0; j < EPT; ++j) {
        if (d8[j] >= 0) {
            int b = d8[j] >> shift;
            unsigned old = atomicAdd(&cnt[b >> 1], 1u << ((b & 1) * 16));
            unsigned intra = (old >> ((b & 1) * 16)) & 0xFFFFu;
            if (intra < CAP)              // capacity clamp (~never)
                ebuf[((unsigned)(rel * NBKT + b) << 10) + intra] =
                    ((unsigned)(d8[j] & dmask) << 18) | (unsigned)s8[j];
        }
    }
}

// ---------------- mid: scatter FIRST (long pole), then proj blocks -------------
__global__ __launch_bounds__(256) void mid_kernel(
    const float* __restrict__ Xp, const float* __restrict__ Xa,
    const __bf16* __restrict__ Bp_t, const __bf16* __restrict__ Ba_t,
    __bf16* __restrict__ YpC, __bf16* __restrict__ YpR, __bf16* __restrict__ YpD,
    __bf16* __restrict__ YaW, __bf16* __restrict__ YaD,
    const int* __restrict__ eiC, const int* __restrict__ eiW,
    const int* __restrict__ eiR, unsigned* __restrict__ gcur,
    unsigned* __restrict__ ebuf, int NP, int NA, int E,
    int nPp, int nPa, int npart) {
    __shared__ unsigned cnt[NPAIR];   // 3.1 KB
    int bid = blockIdx.x;
    if (bid < 3 * npart) {
        scatter_body(eiC, eiW, eiR, gcur, ebuf, E, npart, bid, cnt);
        return;
    }
    bid -= 3 * npart;
    if (bid < nPp) { proj_body<128, 3>(Xp, Bp_t, YpC, YpR, YpD, NP, bid); return; }
    bid -= nPp;
    proj_body<64, 2>(Xa, Ba_t, YaW, YaD, nullptr, NA, bid);
}

// ---------------- merged dual gather: 8 independent Y-row loads in flight ------
// Two independent (list, Y) pairs; per-list accumulation order matches the
// original 4-wide gatherL -> bit-identical results. Short/empty lists fall
// back to index 0 (always a valid Y row); accumulation is predicate-guarded.
__device__ __forceinline__ void gatherCW(const __bf16* __restrict__ YA,
                                         const __bf16* __restrict__ YB,
                                         const unsigned* __restrict__ LA,
                                         const unsigned* __restrict__ LB,
                                         int oA, int nA, int oB, int nB, int l16,
                                         float2& rA, float2& rB) {
    float xA = 0.f, yA = 0.f, xB = 0.f, yB = 0.f;
    int nm = max(nA, nB);
    for (int e = 0; e < nm; e += 4) {
        unsigned a0 = (e + 0 < nA) ? LA[oA + e + 0] : 0u;
        unsigned a1 = (e + 1 < nA) ? LA[oA + e + 1] : 0u;
        unsigned a2 = (e + 2 < nA) ? LA[oA + e + 2] : 0u;
        unsigned a3 = (e + 3 < nA) ? LA[oA + e + 3] : 0u;
        unsigned b0 = (e + 0 < nB) ? LB[oB + e + 0] : 0u;
        unsigned b1 = (e + 1 < nB) ? LB[oB + e + 1] : 0u;
        unsigned b2 = (e + 2 < nB) ? LB[oB + e + 2] : 0u;
        unsigned b3 = (e + 3 < nB) ? LB[oB + e + 3] : 0u;
        bf16x2 vA0 = *(const bf16x2*)(YA + (size_t)a0 * 32 + 2 * l16);
        bf16x2 vA1 = *(const bf16x2*)(YA + (size_t)a1 * 32 + 2 * l16);
        bf16x2 vA2 = *(const bf16x2*)(YA + (size_t)a2 * 32 + 2 * l16);
        bf16x2 vA3 = *(const bf16x2*)(YA + (size_t)a3 * 32 + 2 * l16);
        bf16x2 vB0 = *(const bf16x2*)(YB + (size_t)b0 * 32 + 2 * l16);
        bf16x2 vB1 = *(const bf16x2*)(YB + (size_t)b1 * 32 + 2 * l16);
        bf16x2 vB2 = *(const bf16x2*)(YB + (size_t)b2 * 32 + 2 * l16);
        bf16x2 vB3 = *(const bf16x2*)(YB + (size_t)b3 * 32 + 2 * l16);
        if (e + 0 < nA) { xA += (float)vA0[0]; yA += (float)vA0[1]; }
        if (e + 1 < nA) { xA += (float)vA1[0]; yA += (float)vA1[1]; }
        if (e + 2 < nA) { xA += (float)vA2[0]; yA += (float)vA2[1]; }
        if (e + 3 < nA) { xA += (float)vA3[0]; yA += (float)vA3[1]; }
        if (e + 0 < nB) { xB += (float)vB0[0]; yB += (float)vB0[1]; }
        if (e + 1 < nB) { xB += (float)vB1[0]; yB += (float)vB1[1]; }
        if (e + 2 < nB) { xB += (float)vB2[0]; yB += (float)vB2[1]; }
        if (e + 3 < nB) { xB += (float)vB3[0]; yB += (float)vB3[1]; }
    }
    rA = make_float2(xA, yA);
    rB = make_float2(xB, yB);
}

// ---------------- sagg: fused per-bucket sort + aggregate + collapse -----------
// blocks [0,NBKT): paper bucket b (rel0 cites + rel1 writes), 128 nodes.
// blocks [NBKT,2*NBKT): author bucket b (rel2), 64 nodes, no write-back.
__global__ __launch_bounds__(256) void sagg_kernel(
    const __bf16* __restrict__ YpC, const __bf16* __restrict__ YaW,
    const __bf16* __restrict__ YpD, const __bf16* __restrict__ YpR,
    const __bf16* __restrict__ YaD, unsigned* __restrict__ ebuf,
    const unsigned* __restrict__ gcur, int* __restrict__ nstart, int* __restrict__ ncnt,
    const float* __restrict__ b1l_c, const float* __restrict__ b1l_w,
    const float* __restrict__ b1l_r, const float* __restrict__ uvec,
    float* __restrict__ s_c, float* __restrict__ s_r, float* __restrict__ s_w,
    int NP, int NA) {
    __shared__ unsigned S0[CAP], S1[CAP];
    __shared__ int cnt0[128], exc0[128], cur0[128];
    __shared__ int cnt1[128], exc1[128], cur1[128];
    __shared__ int scan[256];
    const int NPS = NBKT * 128;
    int t = threadIdx.x;
    int sg = t >> 4, l16 = t & 15, c2 = 2 * l16;
    int bid = blockIdx.x;

    if (bid < NBKT) {
        // ---------------- papers ----------------
        int b = bid;
        int st0 = b << 10, st1 = (NBKT + b) << 10;
        int fsh = (b & 1) * 16;
        int n0 = min((int)((gcur[b >> 1] >> fsh) & 0xFFFFu), CAP);
        int n1 = min((int)((gcur[NPAIR + (b >> 1)] >> fsh) & 0xFFFFu), CAP);
        if (t < 128) { cnt0[t] = 0; cnt1[t] = 0; }
        __syncthreads();
        for (int i = t; i < n0; i += 256) atomicAdd(&cnt0[ebuf[st0 + i] >> 18], 1);
        for (int i = t; i < n1; i += 256) atomicAdd(&cnt1[ebuf[st1 + i] >> 18], 1);
        __syncthreads();
        // dual 128-wide exclusive scan with 256 threads
        int own = (t < 128) ? cnt0[t] : cnt1[t - 128];
        scan[t] = own;
        __syncthreads();
        for (int d = 1; d < 128; d <<= 1) {
            int nv = scan[t] + (((t & 127) >= d) ? scan[t - d] : 0);
            __syncthreads();
            scan[t] = nv;
            __syncthreads();
        }
        int excl = scan[t] - own;
        if (t < 128) { exc0[t] = excl; cur0[t] = excl; }
        else         { exc1[t - 128] = excl; cur1[t - 128] = excl; }
        __syncthreads();
        // scatter into sorted LDS lists (plain src)
        for (int i = t; i < n0; i += 256) {
            unsigned w = ebuf[st0 + i];
            int pos = atomicAdd(&cur0[w >> 18], 1);
            S0[pos] = w & SMASK;
        }
        for (int i = t; i < n1; i += 256) {
            unsigned w = ebuf[st1 + i];
            int pos = atomicAdd(&cur1[w >> 18], 1);
            S1[pos] = w & SMASK;
        }
        __syncthreads();
        // fire-and-forget write-back for out_kernel (sorted lists + offsets)
        for (int i = t; i < n0; i += 256) ebuf[st0 + i] = S0[i];
        for (int i = t; i < n1; i += 256) ebuf[st1 + i] = S1[i];
        if (t < 128) {
            nstart[b * 128 + t] = st0 + exc0[t];
            ncnt[b * 128 + t] = cnt0[t];
            nstart[NPS + b * 128 + t] = st1 + exc1[t];
            ncnt[NPS + b * 128 + t] = cnt1[t];
        }
        // gather+combine: subgroup sg owns nodes sg*8 .. sg*8+7, paired
        float u0 = uvec[c2], u1 = uvec[c2 + 1];
        float w0 = uvec[64 + c2], w1 = uvec[64 + c2 + 1];
        float bc0 = b1l_c[c2] + b1l_w[c2], bc1 = b1l_c[c2 + 1] + b1l_w[c2 + 1];
        for (int k = 0; k < 4; ++k) {
            int nd = sg * 8 + 2 * k;
            int g = b * 128 + nd;
            if (g >= NP) break;                 // uniform in 16-lane group
            int nd2 = nd + 1, g2 = g + 1;
            bool v2 = (g2 < NP);                // uniform in 16-lane group
            int nC = cnt0[nd], nW = cnt1[nd];
            int nC2 = v2 ? cnt0[nd2] : 0, nW2 = v2 ? cnt1[nd2] : 0;
            float2 aC, aW, aC2, aW2;
            gatherCW(YpC, YaW, S0, S1, exc0[nd], nC, exc1[nd], nW, l16, aC, aW);
            gatherCW(YpC, YaW, S0, S1, exc0[nd2], nC2, exc1[nd2], nW2, l16, aC2, aW2);
            float rC = 1.f / (float)max(nC, 1), rW = 1.f / (float)max(nW, 1);
            bf16x2 d = *(const bf16x2*)(YpD + (size_t)g * 32 + c2);
            float p0 = fmaxf(aC.x * rC + aW.x * rW + (float)d[0] + bc0, 0.f);
            float p1 = fmaxf(aC.y * rC + aW.y * rW + (float)d[1] + bc1, 0.f);
            float vc = p0 * u0 + p1 * u1;
            float vr = p0 * w0 + p1 * w1;
            float vc2 = 0.f, vr2 = 0.f;
            if (v2) {
                float rC2 = 1.f / (float)max(nC2, 1), rW2 = 1.f / (float)max(nW2, 1);
                bf16x2 d2 = *(const bf16x2*)(YpD + (size_t)g2 * 32 + c2);
                float q0 = fmaxf(aC2.x * rC2 + aW2.x * rW2 + (float)d2[0] + bc0, 0.f);
                float q1 = fmaxf(aC2.y * rC2 + aW2.y * rW2 + (float)d2[1] + bc1, 0.f);
                vc2 = q0 * u0 + q1 * u1;
                vr2 = q0 * w0 + q1 * w1;
            }
            for (int m = 1; m < 16; m <<= 1) {
                vc += __shfl_xor(vc, m, 64);  vr += __shfl_xor(vr, m, 64);
                vc2 += __shfl_xor(vc2, m, 64); vr2 += __shfl_xor(vr2, m, 64);
            }
            if (l16 == 0) {
                s_c[g] = vc; s_r[g] = vr;
                if (v2) { s_c[g2] = vc2; s_r[g2] = vr2; }
            }
        }
    } else {
        // ---------------- authors ----------------
        int b = bid - NBKT;
        int st2 = (2 * NBKT + b) << 10;
        int fsh = (b & 1) * 16;
        int n2 = min((int)((gcur[2 * NPAIR + (b >> 1)] >> fsh) & 0xFFFFu), CAP);
        if (t < 128) { cnt0[t] = 0; cnt1[t] = 0; }
        __syncthreads();
        for (int i = t; i < n2; i += 256) atomicAdd(&cnt0[ebuf[st2 + i] >> 18], 1);
        __syncthreads();
        int own = (t < 128) ? cnt0[t] : 0;
        scan[t] = own;
        __syncthreads();
        for (int d = 1; d < 128; d <<= 1) {
            int nv = scan[t] + (((t & 127) >= d) ? scan[t - d] : 0);
            __syncthreads();
            scan[t] = nv;
            __syncthreads();
        }
        int excl = scan[t] - own;
        if (t < 128) { exc0[t] = excl; cur0[t] = excl; }
        __syncthreads();
        for (int i = t; i < n2; i += 256) {
            unsigned w = ebuf[st2 + i];
            int pos = atomicAdd(&cur0[w >> 18], 1);
            S0[pos] = w & SMASK;
        }
        __syncthreads();
        // no write-back: rel2 sorted list has no downstream consumer
        float uw0 = uvec[32 + c2], uw1 = uvec[32 + c2 + 1];
        float br0 = b1l_r[c2], br1 = b1l_r[c2 + 1];
        for (int k = 0; k < 2; ++k) {
            int nd = sg * 4 + 2 * k;
            int ga = b * 64 + nd;
            if (ga >= NA) break;                // uniform in 16-lane group
            int nd2 = nd + 1, ga2 = ga + 1;
            bool v2 = (ga2 < NA);               // uniform in 16-lane group
            int nR = cnt0[nd], nR2 = v2 ? cnt0[nd2] : 0;
            float2 aR, aR2;
            gatherCW(YpR, YpR, S0, S0, exc0[nd], nR, exc0[nd2], nR2, l16, aR, aR2);
            float rR = 1.f / (float)max(nR, 1);
            bf16x2 d = *(const bf16x2*)(YaD + (size_t)ga * 32 + c2);
            float p0 = fmaxf(aR.x * rR + (float)d[0] + br0, 0.f);
            float p1 = fmaxf(aR.y * rR + (float)d[1] + br1, 0.f);
            float vw = p0 * uw0 + p1 * uw1;
            float vw2 = 0.f;
            if (v2) {
                float rR2 = 1.f / (float)max(nR2, 1);
                bf16x2 d2 = *(const bf16x2*)(YaD + (size_t)ga2 * 32 + c2);
                float q0 = fmaxf(aR2.x * rR2 + (float)d2[0] + br0, 0.f);
                float q1 = fmaxf(aR2.y * rR2 + (float)d2[1] + br1, 0.f);
                vw2 = q0 * uw0 + q1 * uw1;
            }
            for (int m = 1; m < 16; m <<= 1) {
                vw += __shfl_xor(vw, m, 64); vw2 += __shfl_xor(vw2, m, 64);
            }
            if (l16 == 0) {
                s_w[ga] = vw;
                if (v2) s_w[ga2] = vw2;
            }
        }
    }
}

// ---------------- layer-2 scalar aggregation + output: lane per node -----------
__global__ __launch_bounds__(256) void out_kernel(
    const float* __restrict__ s_c, const float* __restrict__ s_w,
    const float* __restrict__ s_r, const unsigned* __restrict__ ebuf,
    const int* __restrict__ nstart, const int* __restrict__ ncnt,
    const float* __restrict__ uvec, float* __restrict__ out, int NP) {
    int gn = blockIdx.x * 256 + threadIdx.x;
    if (gn >= NP) return;
    const int NPS = NBKT * 128;
    int o = nstart[gn], n = ncnt[gn];
    float sC = 0.f;
    for (int e = 0; e < n; e += 8) {
        int m = n - e;
        int a0 = ebuf[o + e];
        int a1 = (m > 1) ? (int)ebuf[o + e + 1] : a0;
        int a2 = (m > 2) ? (int)ebuf[o + e + 2] : a0;
        int a3 = (m > 3) ? (int)ebuf[o + e + 3] : a0;
        int a4 = (m > 4) ? (int)ebuf[o + e + 4] : a0;
        int a5 = (m > 5) ? (int)ebuf[o + e + 5] : a0;
        int a6 = (m > 6) ? (int)ebuf[o + e + 6] : a0;
        int a7 = (m > 7) ? (int)ebuf[o + e + 7] : a0;
        float f0 = s_c[a0], f1 = s_c[a1], f2 = s_c[a2], f3 = s_c[a3];
        float f4 = s_c[a4], f5 = s_c[a5], f6 = s_c[a6], f7 = s_c[a7];
        sC += f0;
        if (m > 1) sC += f1;
        if (m > 2) sC += f2;
        if (m > 3) sC += f3;
        if (m > 4) sC += f4;
        if (m > 5) sC += f5;
        if (m > 6) sC += f6;
        if (m > 7) sC += f7;
    }
    int o2 = nstart[NPS + gn], n2 = ncnt[NPS + gn];
    float sW = 0.f;
    for (int e = 0; e < n2; e += 8) {
        int m = n2 - e;
        int a0 = ebuf[o2 + e];
        int a1 = (m > 1) ? (int)ebuf[o2 + e + 1] : a0;
        int a2 = (m > 2) ? (int)ebuf[o2 + e + 2] : a0;
        int a3 = (m > 3) ? (int)ebuf[o2 + e + 3] : a0;
        int a4 = (m > 4) ? (int)ebuf[o2 + e + 4] : a0;
        int a5 = (m > 5) ? (int)ebuf[o2 + e + 5] : a0;
        int a6 = (m > 6) ? (int)ebuf[o2 + e + 6] : a0;
        int a7 = (m > 7) ? (int)ebuf[o2 + e + 7] : a0;
        float f0 = s_w[a0], f1 = s_w[a1], f2 = s_w[a2], f3 = s_w[a3];
        float f4 = s_w[a4], f5 = s_w[a5], f6 = s_w[a6], f7 = s_w[a7];
        sW += f0;
        if (m > 1) sW += f1;
        if (m > 2) sW += f2;
        if (m > 3) sW += f3;
        if (m > 4) sW += f4;
        if (m > 5) sW += f5;
        if (m > 6) sW += f6;
        if (m > 7) sW += f7;
    }
    out[gn] = sC / (float)max(n, 1) + sW / (float)max(n2, 1) + s_r[gn] + uvec[96];
}

extern "C" void kernel_launch(void* const* d_in, const int* in_sizes, int n_in,
                              void* d_out, int out_size, void* d_ws, size_t ws_size,
                              hipStream_t stream) {
    const float* x_paper  = (const float*)d_in[0];
    const float* x_author = (const float*)d_in[1];
    const int* eiC = (const int*)d_in[2];
    const int* eiW = (const int*)d_in[3];
    const int* eiR = (const int*)d_in[4];
    const float* W1l_c  = (const float*)d_in[5];
    const float* b1l_c  = (const float*)d_in[6];
    const float* W1r_c  = (const float*)d_in[7];
    const float* W1l_w  = (const float*)d_in[8];
    const float* b1l_w  = (const float*)d_in[9];
    const float* W1r_w  = (const float*)d_in[10];
    const float* W1l_r  = (const float*)d_in[11];
    const float* b1l_r  = (const float*)d_in[12];
    const float* W1r_r  = (const float*)d_in[13];
    const float* W2l_c  = (const float*)d_in[14];
    const float* b2l_c  = (const float*)d_in[15];
    const float* W2r_c  = (const float*)d_in[16];
    const float* W2l_w  = (const float*)d_in[17];
    const float* b2l_w  = (const float*)d_in[18];
    const float* W2r_w  = (const float*)d_in[19];
    // d_in[20..22] unused (author layer-2 output not consumed)
    const float* Wh = (const float*)d_in[23];
    const float* bh = (const float*)d_in[24];

    const int NP = in_sizes[0] / 128;
    const int NA = in_sizes[1] / 64;
    const int E  = in_sizes[2] / 2;
    const int npart = (E + SPAN - 1) / SPAN;
    const int nPp = (NP + 63) / 64;
    const int nPa = (NA + 63) / 64;
    const int NNODE = NBKT * 128 * 2 + NBKT * 64;

    char* p = (char*)d_ws;
    auto alloc = [&](size_t bytes) -> void* {
        void* r = (void*)p;
        p += (bytes + 255) & ~(size_t)255;
        return r;
    };
    __bf16* YpC = (__bf16*)alloc((size_t)NP * 32 * 2);
    __bf16* YpR = (__bf16*)alloc((size_t)NP * 32 * 2);
    __bf16* YpD = (__bf16*)alloc((size_t)NP * 32 * 2);
    __bf16* YaW = (__bf16*)alloc((size_t)NA * 32 * 2);
    __bf16* YaD = (__bf16*)alloc((size_t)NA * 32 * 2);
    __bf16* Bp_t = (__bf16*)alloc(96 * 128 * 2);
    __bf16* Ba_t = (__bf16*)alloc(64 * 64 * 2);
    float* uvec = (float*)alloc(128 * 4);
    float* s_c  = (float*)alloc((size_t)NP * 4);
    float* s_r  = (float*)alloc((size_t)NP * 4);
    float* s_w  = (float*)alloc((size_t)NA * 4);
    unsigned* gcur = (unsigned*)alloc((size_t)3 * NPAIR * 4);
    int* nstart = (int*)alloc((size_t)NNODE * 4);
    int* ncnt   = (int*)alloc((size_t)NNODE * 4);
    unsigned* ebuf = (unsigned*)alloc((size_t)3 * NBKT * CAP * 4);   // 19.2 MB

    prep_kernel<<<20, 256, 0, stream>>>(W1l_c, W1l_r, W1r_c, W1r_w, W1l_w, W1r_r,
                                        W2l_c, W2l_w, W2r_c, W2r_w, b2l_c, b2l_w,
                                        Wh, bh, Bp_t, Ba_t, uvec, gcur);

    mid_kernel<<<nPp + nPa + 3 * npart, 256, 0, stream>>>(
        x_paper, x_author, Bp_t, Ba_t, YpC, YpR, YpD, YaW, YaD,
        eiC, eiW, eiR, gcur, ebuf, NP, NA, E, nPp, nPa, npart);

    sagg_kernel<<<2 * NBKT, 256, 0, stream>>>(
        YpC, YaW, YpD, YpR, YaD, ebuf, gcur, nstart, ncnt,
        b1l_c, b1l_w, b1l_r, uvec, s_c, s_r, s_w, NP, NA);

    out_kernel<<<(NP + 255) / 256, 256, 0, stream>>>(
        s_c, s_w, s_r, ebuf, nstart, ncnt, uvec, (float*)d_out, NP);
}

// Round 13
// 360.934 us; speedup vs baseline: 1.1900x; 1.0096x over previous
//
#include <hip/hip_runtime.h>
#include <hip/hip_bf16.h>

// HeteroSAGE collapsed pipeline (float32 I/O, bf16 MFMA + bf16 intermediates):
//   out[i] = mean_cites(s_c[src]) + mean_writes(s_w[src]) + s_r[i] + C0
//   s_c = p1.(W2l_c@Wh), s_r = p1.((W2r_c+W2r_w)@Wh), s_w = a1.(W2l_w@Wh)
//   p1 = relu(mean_c(YpC[src]) + mean_w(YaW[src]) + YpD + b1c + b1w)
//   a1 = relu(mean_r(YpR[src]) + YaD + b1rev)
// R8: direct-claim scatter -> mid 143us. R9: SPAN 2048 -> mid 125us, occ 51%.
// R10: fused sort+agg (VERIFIED). R11-R13: LDS-atomic agg CONVICTED. R14:
// revert verified 397.5. R15: prep grid-stride + gatherCW -> VERIFIED 377.6.
// R16: gcur line-padding REFUTED. R17: cooperative fusion CONVICTED (launch
// no-op under capture). R18: gather-MLP pairing NULL. R19: packed-pair claims
// VERIFIED partial (-6% mid, total 364.4) -- claim chain was minor; mid's
// residual floor attributed to scattered 4B ebuf stores' per-XCD L2 churn.
// R20 (this round): delete the sorted write-back. sagg wrote sorted lists
// (~8MB) + nstart/ncnt (~6MB r+w) solely for out_kernel; out now rebuilds the
// per-bucket sorted lists itself (same hist->scan->LDS-sort preamble, reads
// the same raw ebuf bytes it read before) and sums s_c/s_w from LDS. Same
// nondeterminism class as existing cur0 atomics. mid untouched.

#define SPAN  2048
#define EPT   8           // SPAN / 256 edges per thread
#define NBKT  1563        // ceil(200000/128) == ceil(100000/64)
#define NPAIR 782         // ceil(NBKT/2) packed cursor words per relation
#define CAP   1024        // padded region per (rel,bucket); Poisson(640), 15 sigma
#define SMASK 0x3FFFF     // 18-bit src index (200000 < 2^18)

typedef __bf16 bf16x8 __attribute__((ext_vector_type(8)));
typedef __bf16 bf16x2 __attribute__((ext_vector_type(2)));
typedef float f32x4 __attribute__((ext_vector_type(4)));

// ---------------- prep: weights -> bf16, head vecs, cursor init ----------------
// Grid-strided across blocks; only block 0 computes the 32-wide uvec collapse.
__global__ void prep_kernel(const float* W1l_c, const float* W1l_rev,
                            const float* W1r_c, const float* W1r_w,
                            const float* W1l_w, const float* W1r_rev,
                            const float* W2l_c, const float* W2l_w,
                            const float* W2r_c, const float* W2r_w,
                            const float* b2l_c, const float* b2l_w,
                            const float* Wh, const float* bh,
                            __bf16* Bp_t, __bf16* Ba_t, float* uvec,
                            unsigned* gcur) {
    int tid = blockIdx.x * 256 + threadIdx.x;
    int nthr = gridDim.x * 256;
    for (int i = tid; i < 3 * NPAIR; i += nthr) gcur[i] = 0u;  // packed intra-lens
    for (int idx = tid; idx < 96 * 128; idx += nthr) {   // Bp_t[n][k] n<96,k<128
        int n = idx >> 7, k = idx & 127;
        float v;
        if (n < 32)      v = W1l_c[k * 32 + n];
        else if (n < 64) v = W1l_rev[k * 32 + (n - 32)];
        else             v = W1r_c[k * 32 + (n - 64)] + W1r_w[k * 32 + (n - 64)];
        Bp_t[n * 128 + k] = (__bf16)v;
    }
    for (int idx = tid; idx < 64 * 64; idx += nthr) {    // Ba_t[n][k] n<64,k<64
        int n = idx >> 6, k = idx & 63;
        float v = (n < 32) ? W1l_w[k * 32 + n] : W1r_rev[k * 32 + (n - 32)];
        Ba_t[n * 64 + k] = (__bf16)v;
    }
    if (blockIdx.x == 0 && threadIdx.x < 32) {
        int t = threadIdx.x;
        float uc = 0.f, uw = 0.f, ur = 0.f;
        for (int j = 0; j < 32; ++j) {
            float wh = Wh[j];
            uc += W2l_c[t * 32 + j] * wh;
            uw += W2l_w[t * 32 + j] * wh;
            ur += (W2r_c[t * 32 + j] + W2r_w[t * 32 + j]) * wh;
        }
        uvec[t] = uc; uvec[32 + t] = uw; uvec[64 + t] = ur;
        if (t == 0) {
            float c0 = bh[0];
            for (int j = 0; j < 32; ++j) c0 += (b2l_c[j] + b2l_w[j]) * Wh[j];
            uvec[96] = c0;
        }
    }
}

// ---------------- proj body (MFMA 16x16x32 bf16), 32-col group split -----------
template <int K, int NG>
__device__ __forceinline__ void proj_body(const float* __restrict__ X,
                                          const __bf16* __restrict__ Bt,
                                          __bf16* __restrict__ D0,
                                          __bf16* __restrict__ D1,
                                          __bf16* __restrict__ D2, int M, int bid) {
    constexpr int NT = NG * 2, KT = K / 32;
    int lane = threadIdx.x & 63;
    int wave = (bid * 256 + (int)threadIdx.x) >> 6;
    int m0 = wave * 16;
    if (m0 + 16 > M) return;  // M % 16 == 0 here
    int lr = lane & 15;
    int quad = lane >> 4;

    bf16x8 bfrag[NT][KT];
#pragma unroll
    for (int ct = 0; ct < NT; ++ct)
#pragma unroll
        for (int ks = 0; ks < KT; ++ks)
            bfrag[ct][ks] = *(const bf16x8*)(Bt + (ct * 16 + lr) * K + ks * 32 + quad * 8);

    bf16x8 afrag[KT];
    const float* xrow = X + (size_t)(m0 + lr) * K + quad * 8;
#pragma unroll
    for (int ks = 0; ks < KT; ++ks) {
        f32x4 lo = *(const f32x4*)(xrow + ks * 32);
        f32x4 hi = *(const f32x4*)(xrow + ks * 32 + 4);
        bf16x8 a;
#pragma unroll
        for (int j = 0; j < 4; ++j) { a[j] = (__bf16)lo[j]; a[4 + j] = (__bf16)hi[j]; }
        afrag[ks] = a;
    }

    int odd = lane & 1;
#pragma unroll
    for (int ct = 0; ct < NT; ++ct) {
        f32x4 acc = {0.f, 0.f, 0.f, 0.f};
#pragma unroll
        for (int ks = 0; ks < KT; ++ks)
            acc = __builtin_amdgcn_mfma_f32_16x16x32_bf16(afrag[ks], bfrag[ct][ks], acc, 0, 0, 0);
        __bf16* D = ((ct >> 1) == 0) ? D0 : (((ct >> 1) == 1) ? D1 : D2);
        int col = (ct & 1) * 16 + lr;
        int cw = col & ~1;                 // even col of the lane pair
        int rbase = m0 + quad * 4;
        float o0 = __shfl_xor(acc[0], 1, 64);
        float o1 = __shfl_xor(acc[1], 1, 64);
        float o2 = __shfl_xor(acc[2], 1, 64);
        float o3 = __shfl_xor(acc[3], 1, 64);
        float s0 = odd ? o2 : acc[0], t0 = odd ? acc[2] : o0;   // row rb+0
        float s1 = odd ? o3 : acc[1], t1 = odd ? acc[3] : o1;   // row rb+1
        int rb = rbase + odd * 2;
        bf16x2 v0; v0[0] = (__bf16)s0; v0[1] = (__bf16)t0;
        bf16x2 v1; v1[0] = (__bf16)s1; v1[1] = (__bf16)t1;
        *(bf16x2*)(D + (size_t)(rb + 0) * 32 + cw) = v0;
        *(bf16x2*)(D + (size_t)(rb + 1) * 32 + cw) = v1;
    }
}

// ------ scatter body: packed-pair direct-claim, arrival-order bucket fill ------
// gcur[rel*NPAIR + (b>>1)] holds two 16-bit intra-region cursors. Counts per
// bucket <= ~800 << 2^16, so packed atomicAdd never carries across fields and
// the returned old value gives exact per-field prefix sums.
__device__ void scatter_body(const int* __restrict__ eiC, const int* __restrict__ eiW,
                             const int* __restrict__ eiR, unsigned* __restrict__ gcur,
                             unsigned* __restrict__ ebuf, int E, int npart, int bid,
                             unsigned* cnt) {
    int rel = bid / npart, blk = bid % npart;
    const int* ei = rel == 0 ? eiC : (rel == 1 ? eiW : eiR);
    int shift = (rel == 2) ? 6 : 7;
    unsigned dmask = (1u << shift) - 1;
    int t = threadIdx.x;
    int e0 = blk * SPAN, e1 = min(E, e0 + SPAN);
    for (int i = t; i < NPAIR; i += 256) cnt[i] = 0u;
    __syncthreads();
    int d8[EPT], s8[EPT];
#pragma unroll
    for (int j = 0; j < EPT; ++j) {       // all 16 loads in flight first
        int e = e0 + t + j * 256;
        d8[j] = (e < e1) ? ei[E + e] : -1;
        s8[j] = (e < e1) ? ei[e] : 0;
    }
#pragma unroll
    for (int j = 0; j < EPT; ++j) {       // packed hist
        if (d8[j] >= 0) {
            int b = d8[j] >> shift;
            atomicAdd(&cnt[b >> 1], 1u << ((b & 1) * 16));
        }
    }
    __syncthreads();
    // packed claim: one global atomic per non-empty PAIR; old -> per-field base
    unsigned* gp = gcur + rel * NPAIR;
    for (int i = t; i < NPAIR; i += 256) {
        unsigned c = cnt[i];
        cnt[i] = c ? atomicAdd(&gp[i], c) : 0u;
    }
    __syncthreads();
#pragma unroll
    for (int j = 0; j < EPT; ++j) {
        if (d8[j] >= 0) {
            int b = d8[j] >> shift;
            unsigned old = atomicAdd(&cnt[b >> 1], 1u << ((b & 1) * 16));
            unsigned intra = (old >> ((b & 1) * 16)) & 0xFFFFu;
            if (intra < CAP)              // capacity clamp (~never)
                ebuf[((unsigned)(rel * NBKT + b) << 10) + intra] =
                    ((unsigned)(d8[j] & dmask) << 18) | (unsigned)s8[j];
        }
    }
}

// ---------------- mid: scatter FIRST (long pole), then proj blocks -------------
__global__ __launch_bounds__(256) void mid_kernel(
    const float* __restrict__ Xp, const float* __restrict__ Xa,
    const __bf16* __restrict__ Bp_t, const __bf16* __restrict__ Ba_t,
    __bf16* __restrict__ YpC, __bf16* __restrict__ YpR, __bf16* __restrict__ YpD,
    __bf16* __restrict__ YaW, __bf16* __restrict__ YaD,
    const int* __restrict__ eiC, const int* __restrict__ eiW,
    const int* __restrict__ eiR, unsigned* __restrict__ gcur,
    unsigned* __restrict__ ebuf, int NP, int NA, int E,
    int nPp, int nPa, int npart) {
    __shared__ unsigned cnt[NPAIR];   // 3.1 KB
    int bid = blockIdx.x;
    if (bid < 3 * npart) {
        scatter_body(eiC, eiW, eiR, gcur, ebuf, E, npart, bid, cnt);
        return;
    }
    bid -= 3 * npart;
    if (bid < nPp) { proj_body<128, 3>(Xp, Bp_t, YpC, YpR, YpD, NP, bid); return; }
    bid -= nPp;
    proj_body<64, 2>(Xa, Ba_t, YaW, YaD, nullptr, NA, bid);
}

// ---------------- merged dual gather: 8 independent Y-row loads in flight ------
// Two independent (list, Y) pairs; per-list accumulation order matches the
// original 4-wide gatherL -> bit-identical results. Short/empty lists fall
// back to index 0 (always a valid Y row); accumulation is predicate-guarded.
__device__ __forceinline__ void gatherCW(const __bf16* __restrict__ YA,
                                         const __bf16* __restrict__ YB,
                                         const unsigned* __restrict__ LA,
                                         const unsigned* __restrict__ LB,
                                         int oA, int nA, int oB, int nB, int l16,
                                         float2& rA, float2& rB) {
    float xA = 0.f, yA = 0.f, xB = 0.f, yB = 0.f;
    int nm = max(nA, nB);
    for (int e = 0; e < nm; e += 4) {
        unsigned a0 = (e + 0 < nA) ? LA[oA + e + 0] : 0u;
        unsigned a1 = (e + 1 < nA) ? LA[oA + e + 1] : 0u;
        unsigned a2 = (e + 2 < nA) ? LA[oA + e + 2] : 0u;
        unsigned a3 = (e + 3 < nA) ? LA[oA + e + 3] : 0u;
        unsigned b0 = (e + 0 < nB) ? LB[oB + e + 0] : 0u;
        unsigned b1 = (e + 1 < nB) ? LB[oB + e + 1] : 0u;
        unsigned b2 = (e + 2 < nB) ? LB[oB + e + 2] : 0u;
        unsigned b3 = (e + 3 < nB) ? LB[oB + e + 3] : 0u;
        bf16x2 vA0 = *(const bf16x2*)(YA + (size_t)a0 * 32 + 2 * l16);
        bf16x2 vA1 = *(const bf16x2*)(YA + (size_t)a1 * 32 + 2 * l16);
        bf16x2 vA2 = *(const bf16x2*)(YA + (size_t)a2 * 32 + 2 * l16);
        bf16x2 vA3 = *(const bf16x2*)(YA + (size_t)a3 * 32 + 2 * l16);
        bf16x2 vB0 = *(const bf16x2*)(YB + (size_t)b0 * 32 + 2 * l16);
        bf16x2 vB1 = *(const bf16x2*)(YB + (size_t)b1 * 32 + 2 * l16);
        bf16x2 vB2 = *(const bf16x2*)(YB + (size_t)b2 * 32 + 2 * l16);
        bf16x2 vB3 = *(const bf16x2*)(YB + (size_t)b3 * 32 + 2 * l16);
        if (e + 0 < nA) { xA += (float)vA0[0]; yA += (float)vA0[1]; }
        if (e + 1 < nA) { xA += (float)vA1[0]; yA += (float)vA1[1]; }
        if (e + 2 < nA) { xA += (float)vA2[0]; yA += (float)vA2[1]; }
        if (e + 3 < nA) { xA += (float)vA3[0]; yA += (float)vA3[1]; }
        if (e + 0 < nB) { xB += (float)vB0[0]; yB += (float)vB0[1]; }
        if (e + 1 < nB) { xB += (float)vB1[0]; yB += (float)vB1[1]; }
        if (e + 2 < nB) { xB += (float)vB2[0]; yB += (float)vB2[1]; }
        if (e + 3 < nB) { xB += (float)vB3[0]; yB += (float)vB3[1]; }
    }
    rA = make_float2(xA, yA);
    rB = make_float2(xB, yB);
}

// ---------------- sagg: fused per-bucket sort + aggregate + collapse -----------
// blocks [0,NBKT): paper bucket b (rel0 cites + rel1 writes), 128 nodes.
// blocks [NBKT,2*NBKT): author bucket b (rel2), 64 nodes.
// No write-back, no nstart/ncnt: out_kernel re-sorts its buckets itself.
__global__ __launch_bounds__(256) void sagg_kernel(
    const __bf16* __restrict__ YpC, const __bf16* __restrict__ YaW,
    const __bf16* __restrict__ YpD, const __bf16* __restrict__ YpR,
    const __bf16* __restrict__ YaD, const unsigned* __restrict__ ebuf,
    const unsigned* __restrict__ gcur,
    const float* __restrict__ b1l_c, const float* __restrict__ b1l_w,
    const float* __restrict__ b1l_r, const float* __restrict__ uvec,
    float* __restrict__ s_c, float* __restrict__ s_r, float* __restrict__ s_w,
    int NP, int NA) {
    __shared__ unsigned S0[CAP], S1[CAP];
    __shared__ int cnt0[128], exc0[128], cur0[128];
    __shared__ int cnt1[128], exc1[128], cur1[128];
    __shared__ int scan[256];
    int t = threadIdx.x;
    int sg = t >> 4, l16 = t & 15, c2 = 2 * l16;
    int bid = blockIdx.x;

    if (bid < NBKT) {
        // ---------------- papers ----------------
        int b = bid;
        int st0 = b << 10, st1 = (NBKT + b) << 10;
        int fsh = (b & 1) * 16;
        int n0 = min((int)((gcur[b >> 1] >> fsh) & 0xFFFFu), CAP);
        int n1 = min((int)((gcur[NPAIR + (b >> 1)] >> fsh) & 0xFFFFu), CAP);
        if (t < 128) { cnt0[t] = 0; cnt1[t] = 0; }
        __syncthreads();
        for (int i = t; i < n0; i += 256) atomicAdd(&cnt0[ebuf[st0 + i] >> 18], 1);
        for (int i = t; i < n1; i += 256) atomicAdd(&cnt1[ebuf[st1 + i] >> 18], 1);
        __syncthreads();
        // dual 128-wide exclusive scan with 256 threads
        int own = (t < 128) ? cnt0[t] : cnt1[t - 128];
        scan[t] = own;
        __syncthreads();
        for (int d = 1; d < 128; d <<= 1) {
            int nv = scan[t] + (((t & 127) >= d) ? scan[t - d] : 0);
            __syncthreads();
            scan[t] = nv;
            __syncthreads();
        }
        int excl = scan[t] - own;
        if (t < 128) { exc0[t] = excl; cur0[t] = excl; }
        else         { exc1[t - 128] = excl; cur1[t - 128] = excl; }
        __syncthreads();
        // scatter into sorted LDS lists (plain src)
        for (int i = t; i < n0; i += 256) {
            unsigned w = ebuf[st0 + i];
            int pos = atomicAdd(&cur0[w >> 18], 1);
            S0[pos] = w & SMASK;
        }
        for (int i = t; i < n1; i += 256) {
            unsigned w = ebuf[st1 + i];
            int pos = atomicAdd(&cur1[w >> 18], 1);
            S1[pos] = w & SMASK;
        }
        __syncthreads();
        // gather+combine: subgroup sg owns nodes sg*8 .. sg*8+7, paired
        float u0 = uvec[c2], u1 = uvec[c2 + 1];
        float w0 = uvec[64 + c2], w1 = uvec[64 + c2 + 1];
        float bc0 = b1l_c[c2] + b1l_w[c2], bc1 = b1l_c[c2 + 1] + b1l_w[c2 + 1];
        for (int k = 0; k < 4; ++k) {
            int nd = sg * 8 + 2 * k;
            int g = b * 128 + nd;
            if (g >= NP) break;                 // uniform in 16-lane group
            int nd2 = nd + 1, g2 = g + 1;
            bool v2 = (g2 < NP);                // uniform in 16-lane group
            int nC = cnt0[nd], nW = cnt1[nd];
            int nC2 = v2 ? cnt0[nd2] : 0, nW2 = v2 ? cnt1[nd2] : 0;
            float2 aC, aW, aC2, aW2;
            gatherCW(YpC, YaW, S0, S1, exc0[nd], nC, exc1[nd], nW, l16, aC, aW);
            gatherCW(YpC, YaW, S0, S1, exc0[nd2], nC2, exc1[nd2], nW2, l16, aC2, aW2);
            float rC = 1.f / (float)max(nC, 1), rW = 1.f / (float)max(nW, 1);
            bf16x2 d = *(const bf16x2*)(YpD + (size_t)g * 32 + c2);
            float p0 = fmaxf(aC.x * rC + aW.x * rW + (float)d[0] + bc0, 0.f);
            float p1 = fmaxf(aC.y * rC + aW.y * rW + (float)d[1] + bc1, 0.f);
            float vc = p0 * u0 + p1 * u1;
            float vr = p0 * w0 + p1 * w1;
            float vc2 = 0.f, vr2 = 0.f;
            if (v2) {
                float rC2 = 1.f / (float)max(nC2, 1), rW2 = 1.f / (float)max(nW2, 1);
                bf16x2 d2 = *(const bf16x2*)(YpD + (size_t)g2 * 32 + c2);
                float q0 = fmaxf(aC2.x * rC2 + aW2.x * rW2 + (float)d2[0] + bc0, 0.f);
                float q1 = fmaxf(aC2.y * rC2 + aW2.y * rW2 + (float)d2[1] + bc1, 0.f);
                vc2 = q0 * u0 + q1 * u1;
                vr2 = q0 * w0 + q1 * w1;
            }
            for (int m = 1; m < 16; m <<= 1) {
                vc += __shfl_xor(vc, m, 64);  vr += __shfl_xor(vr, m, 64);
                vc2 += __shfl_xor(vc2, m, 64); vr2 += __shfl_xor(vr2, m, 64);
            }
            if (l16 == 0) {
                s_c[g] = vc; s_r[g] = vr;
                if (v2) { s_c[g2] = vc2; s_r[g2] = vr2; }
            }
        }
    } else {
        // ---------------- authors ----------------
        int b = bid - NBKT;
        int st2 = (2 * NBKT + b) << 10;
        int fsh = (b & 1) * 16;
        int n2 = min((int)((gcur[2 * NPAIR + (b >> 1)] >> fsh) & 0xFFFFu), CAP);
        if (t < 128) { cnt0[t] = 0; cnt1[t] = 0; }
        __syncthreads();
        for (int i = t; i < n2; i += 256) atomicAdd(&cnt0[ebuf[st2 + i] >> 18], 1);
        __syncthreads();
        int own = (t < 128) ? cnt0[t] : 0;
        scan[t] = own;
        __syncthreads();
        for (int d = 1; d < 128; d <<= 1) {
            int nv = scan[t] + (((t & 127) >= d) ? scan[t - d] : 0);
            __syncthreads();
            scan[t] = nv;
            __syncthreads();
        }
        int excl = scan[t] - own;
        if (t < 128) { exc0[t] = excl; cur0[t] = excl; }
        __syncthreads();
        for (int i = t; i < n2; i += 256) {
            unsigned w = ebuf[st2 + i];
            int pos = atomicAdd(&cur0[w >> 18], 1);
            S0[pos] = w & SMASK;
        }
        __syncthreads();
        float uw0 = uvec[32 + c2], uw1 = uvec[32 + c2 + 1];
        float br0 = b1l_r[c2], br1 = b1l_r[c2 + 1];
        for (int k = 0; k < 2; ++k) {
            int nd = sg * 4 + 2 * k;
            int ga = b * 64 + nd;
            if (ga >= NA) break;                // uniform in 16-lane group
            int nd2 = nd + 1, ga2 = ga + 1;
            bool v2 = (ga2 < NA);               // uniform in 16-lane group
            int nR = cnt0[nd], nR2 = v2 ? cnt0[nd2] : 0;
            float2 aR, aR2;
            gatherCW(YpR, YpR, S0, S0, exc0[nd], nR, exc0[nd2], nR2, l16, aR, aR2);
            float rR = 1.f / (float)max(nR, 1);
            bf16x2 d = *(const bf16x2*)(YaD + (size_t)ga * 32 + c2);
            float p0 = fmaxf(aR.x * rR + (float)d[0] + br0, 0.f);
            float p1 = fmaxf(aR.y * rR + (float)d[1] + br1, 0.f);
            float vw = p0 * uw0 + p1 * uw1;
            float vw2 = 0.f;
            if (v2) {
                float rR2 = 1.f / (float)max(nR2, 1);
                bf16x2 d2 = *(const bf16x2*)(YaD + (size_t)ga2 * 32 + c2);
                float q0 = fmaxf(aR2.x * rR2 + (float)d2[0] + br0, 0.f);
                float q1 = fmaxf(aR2.y * rR2 + (float)d2[1] + br1, 0.f);
                vw2 = q0 * uw0 + q1 * uw1;
            }
            for (int m = 1; m < 16; m <<= 1) {
                vw += __shfl_xor(vw, m, 64); vw2 += __shfl_xor(vw2, m, 64);
            }
            if (l16 == 0) {
                s_w[ga] = vw;
                if (v2) s_w[ga2] = vw2;
            }
        }
    }
}

// ---------- out: per-bucket re-sort from raw ebuf + scalar aggregation ---------
// Block b: sort rel0/rel1 regions of paper bucket b into LDS (same preamble as
// sagg), then node-thread t sums s_c/s_w over its LDS lists (8-wide) and
// writes out[b*128+t]. No nstart/ncnt, no sorted write-back needed.
__global__ __launch_bounds__(256) void out_kernel(
    const float* __restrict__ s_c, const float* __restrict__ s_w,
    const float* __restrict__ s_r, const unsigned* __restrict__ ebuf,
    const unsigned* __restrict__ gcur,
    const float* __restrict__ uvec, float* __restrict__ out, int NP) {
    __shared__ unsigned S0[CAP], S1[CAP];
    __shared__ int cnt0[128], exc0[128], cur0[128];
    __shared__ int cnt1[128], exc1[128], cur1[128];
    __shared__ int scan[256];
    int t = threadIdx.x;
    int b = blockIdx.x;
    int st0 = b << 10, st1 = (NBKT + b) << 10;
    int fsh = (b & 1) * 16;
    int n0 = min((int)((gcur[b >> 1] >> fsh) & 0xFFFFu), CAP);
    int n1 = min((int)((gcur[NPAIR + (b >> 1)] >> fsh) & 0xFFFFu), CAP);
    if (t < 128) { cnt0[t] = 0; cnt1[t] = 0; }
    __syncthreads();
    for (int i = t; i < n0; i += 256) atomicAdd(&cnt0[ebuf[st0 + i] >> 18], 1);
    for (int i = t; i < n1; i += 256) atomicAdd(&cnt1[ebuf[st1 + i] >> 18], 1);
    __syncthreads();
    int own = (t < 128) ? cnt0[t] : cnt1[t - 128];
    scan[t] = own;
    __syncthreads();
    for (int d = 1; d < 128; d <<= 1) {
        int nv = scan[t] + (((t & 127) >= d) ? scan[t - d] : 0);
        __syncthreads();
        scan[t] = nv;
        __syncthreads();
    }
    int excl = scan[t] - own;
    if (t < 128) { exc0[t] = excl; cur0[t] = excl; }
    else         { exc1[t - 128] = excl; cur1[t - 128] = excl; }
    __syncthreads();
    for (int i = t; i < n0; i += 256) {
        unsigned w = ebuf[st0 + i];
        int pos = atomicAdd(&cur0[w >> 18], 1);
        S0[pos] = w & SMASK;
    }
    for (int i = t; i < n1; i += 256) {
        unsigned w = ebuf[st1 + i];
        int pos = atomicAdd(&cur1[w >> 18], 1);
        S1[pos] = w & SMASK;
    }
    __syncthreads();
    if (t < 128) {
        int g = b * 128 + t;
        if (g < NP) {
            int o = exc0[t], n = cnt0[t];
            float sC = 0.f;
            for (int e = 0; e < n; e += 8) {
                int m = n - e;
                int a0 = S0[o + e];
                int a1 = (m > 1) ? (int)S0[o + e + 1] : a0;
                int a2 = (m > 2) ? (int)S0[o + e + 2] : a0;
                int a3 = (m > 3) ? (int)S0[o + e + 3] : a0;
                int a4 = (m > 4) ? (int)S0[o + e + 4] : a0;
                int a5 = (m > 5) ? (int)S0[o + e + 5] : a0;
                int a6 = (m > 6) ? (int)S0[o + e + 6] : a0;
                int a7 = (m > 7) ? (int)S0[o + e + 7] : a0;
                float f0 = s_c[a0], f1 = s_c[a1], f2 = s_c[a2], f3 = s_c[a3];
                float f4 = s_c[a4], f5 = s_c[a5], f6 = s_c[a6], f7 = s_c[a7];
                sC += f0;
                if (m > 1) sC += f1;
                if (m > 2) sC += f2;
                if (m > 3) sC += f3;
                if (m > 4) sC += f4;
                if (m > 5) sC += f5;
                if (m > 6) sC += f6;
                if (m > 7) sC += f7;
            }
            int o2 = exc1[t], n2 = cnt1[t];
            float sW = 0.f;
            for (int e = 0; e < n2; e += 8) {
                int m = n2 - e;
                int a0 = S1[o2 + e];
                int a1 = (m > 1) ? (int)S1[o2 + e + 1] : a0;
                int a2 = (m > 2) ? (int)S1[o2 + e + 2] : a0;
                int a3 = (m > 3) ? (int)S1[o2 + e + 3] : a0;
                int a4 = (m > 4) ? (int)S1[o2 + e + 4] : a0;
                int a5 = (m > 5) ? (int)S1[o2 + e + 5] : a0;
                int a6 = (m > 6) ? (int)S1[o2 + e + 6] : a0;
                int a7 = (m > 7) ? (int)S1[o2 + e + 7] : a0;
                float f0 = s_w[a0], f1 = s_w[a1], f2 = s_w[a2], f3 = s_w[a3];
                float f4 = s_w[a4], f5 = s_w[a5], f6 = s_w[a6], f7 = s_w[a7];
                sW += f0;
                if (m > 1) sW += f1;
                if (m > 2) sW += f2;
                if (m > 3) sW += f3;
                if (m > 4) sW += f4;
                if (m > 5) sW += f5;
                if (m > 6) sW += f6;
                if (m > 7) sW += f7;
            }
            out[g] = sC / (float)max(n, 1) + sW / (float)max(n2, 1)
                   + s_r[g] + uvec[96];
        }
    }
}

extern "C" void kernel_launch(void* const* d_in, const int* in_sizes, int n_in,
                              void* d_out, int out_size, void* d_ws, size_t ws_size,
                              hipStream_t stream) {
    const float* x_paper  = (const float*)d_in[0];
    const float* x_author = (const float*)d_in[1];
    const int* eiC = (const int*)d_in[2];
    const int* eiW = (const int*)d_in[3];
    const int* eiR = (const int*)d_in[4];
    const float* W1l_c  = (const float*)d_in[5];
    const float* b1l_c  = (const float*)d_in[6];
    const float* W1r_c  = (const float*)d_in[7];
    const float* W1l_w  = (const float*)d_in[8];
    const float* b1l_w  = (const float*)d_in[9];
    const float* W1r_w  = (const float*)d_in[10];
    const float* W1l_r  = (const float*)d_in[11];
    const float* b1l_r  = (const float*)d_in[12];
    const float* W1r_r  = (const float*)d_in[13];
    const float* W2l_c  = (const float*)d_in[14];
    const float* b2l_c  = (const float*)d_in[15];
    const float* W2r_c  = (const float*)d_in[16];
    const float* W2l_w  = (const float*)d_in[17];
    const float* b2l_w  = (const float*)d_in[18];
    const float* W2r_w  = (const float*)d_in[19];
    // d_in[20..22] unused (author layer-2 output not consumed)
    const float* Wh = (const float*)d_in[23];
    const float* bh = (const float*)d_in[24];

    const int NP = in_sizes[0] / 128;
    const int NA = in_sizes[1] / 64;
    const int E  = in_sizes[2] / 2;
    const int npart = (E + SPAN - 1) / SPAN;
    const int nPp = (NP + 63) / 64;
    const int nPa = (NA + 63) / 64;

    char* p = (char*)d_ws;
    auto alloc = [&](size_t bytes) -> void* {
        void* r = (void*)p;
        p += (bytes + 255) & ~(size_t)255;
        return r;
    };
    __bf16* YpC = (__bf16*)alloc((size_t)NP * 32 * 2);
    __bf16* YpR = (__bf16*)alloc((size_t)NP * 32 * 2);
    __bf16* YpD = (__bf16*)alloc((size_t)NP * 32 * 2);
    __bf16* YaW = (__bf16*)alloc((size_t)NA * 32 * 2);
    __bf16* YaD = (__bf16*)alloc((size_t)NA * 32 * 2);
    __bf16* Bp_t = (__bf16*)alloc(96 * 128 * 2);
    __bf16* Ba_t = (__bf16*)alloc(64 * 64 * 2);
    float* uvec = (float*)alloc(128 * 4);
    float* s_c  = (float*)alloc((size_t)NP * 4);
    float* s_r  = (float*)alloc((size_t)NP * 4);
    float* s_w  = (float*)alloc((size_t)NA * 4);
    unsigned* gcur = (unsigned*)alloc((size_t)3 * NPAIR * 4);
    unsigned* ebuf = (unsigned*)alloc((size_t)3 * NBKT * CAP * 4);   // 19.2 MB

    prep_kernel<<<20, 256, 0, stream>>>(W1l_c, W1l_r, W1r_c, W1r_w, W1l_w, W1r_r,
                                        W2l_c, W2l_w, W2r_c, W2r_w, b2l_c, b2l_w,
                                        Wh, bh, Bp_t, Ba_t, uvec, gcur);

    mid_kernel<<<nPp + nPa + 3 * npart, 256, 0, stream>>>(
        x_paper, x_author, Bp_t, Ba_t, YpC, YpR, YpD, YaW, YaD,
        eiC, eiW, eiR, gcur, ebuf, NP, NA, E, nPp, nPa, npart);

    sagg_kernel<<<2 * NBKT, 256, 0, stream>>>(
        YpC, YaW, YpD, YpR, YaD, ebuf, gcur,
        b1l_c, b1l_w, b1l_r, uvec, s_c, s_r, s_w, NP, NA);

    out_kernel<<<NBKT, 256, 0, stream>>>(
        s_c, s_w, s_r, ebuf, gcur, uvec, (float*)d_out, NP);
}